// Round 8
// baseline (174.196 us; speedup 1.0000x reference)
//
#include <hip/hip_runtime.h>

typedef __attribute__((ext_vector_type(4))) float f32x4;
typedef __attribute__((ext_vector_type(8))) short s16x8;

#define GLDS(gsrc, ldst) \
  __builtin_amdgcn_global_load_lds((const __attribute__((address_space(1))) void*)(gsrc), \
                                   (__attribute__((address_space(3))) void*)(ldst), 16, 0, 0)

__device__ __forceinline__ ushort f2bf(float f) {
  union { float f; unsigned u; } x; x.f = f;
  unsigned r = (x.u + 0x7FFFu + ((x.u >> 16) & 1u)) >> 16;
  return (ushort)r;
}

template<int N> __device__ __forceinline__ void waitvm() {
  if constexpr (N == 0) asm volatile("s_waitcnt vmcnt(0)" ::: "memory");
  else if constexpr (N == 4) asm volatile("s_waitcnt vmcnt(4)" ::: "memory");
  else if constexpr (N == 8) asm volatile("s_waitcnt vmcnt(8)" ::: "memory");
}

// ---------------- cast f32 -> bf16 ----------------
__global__ __launch_bounds__(256) void castk(const float* __restrict__ in,
                                             ushort* __restrict__ outp, int n) {
  int i = (blockIdx.x * 256 + threadIdx.x) * 4;
  if (i >= n) return;
  float4 v = *(const float4*)(in + i);
  ushort4 r;
  r.x = f2bf(v.x); r.y = f2bf(v.y); r.z = f2bf(v.z); r.w = f2bf(v.w);
  *(ushort4*)(outp + i) = r;
}

__global__ __launch_bounds__(256) void castw(const float* __restrict__ w0, const float* __restrict__ w1,
                                             const float* __restrict__ w2, const float* __restrict__ w3,
                                             ushort* __restrict__ o0, ushort* __restrict__ o1,
                                             ushort* __restrict__ o2, ushort* __restrict__ o3) {
  int bid = blockIdx.x;
  int sel = bid >> 10;
  const float* in = (sel == 0) ? w0 : (sel == 1) ? w1 : (sel == 2) ? w2 : w3;
  ushort* outp    = (sel == 0) ? o0 : (sel == 1) ? o1 : (sel == 2) ? o2 : o3;
  int i = ((bid & 1023) * 256 + threadIdx.x) * 4;
  float4 v = *(const float4*)(in + i);
  ushort4 r;
  r.x = f2bf(v.x); r.y = f2bf(v.y); r.z = f2bf(v.z); r.w = f2bf(v.w);
  *(ushort4*)(outp + i) = r;
}

// ---------------- GEMM 256x256, quadrant 8-phase, BK=64 ----------------
// Same schedule as round 7 (vmcnt timeline verified); __launch_bounds__(512,2)
// raises the VGPR cap to 256 (round 7's cap=128 spilled ~90 regs -> scratch).
template<int OUTBF16>
__global__ __launch_bounds__(512, 2) void gemmQ(
    const ushort* __restrict__ A, const ushort* __restrict__ Bt,
    const float* __restrict__ bias0, const float* __restrict__ bias1,
    const float* __restrict__ bias2,
    void* __restrict__ Cout, int M, int N, int K, int nxn)
{
  constexpr int SB = 32768;  // buffer stride (ushorts): A 16384 + B 16384
  __shared__ __align__(16) ushort lds[65536];

  const int tid = threadIdx.x;
  const int w = tid >> 6, lane = tid & 63;
  const int lrow = lane & 15, lg = lane >> 4;
  const int wm2a = (w >> 2) * 64, wn2a = (w & 3) * 32;
  const int cpx = gridDim.x >> 3;
  const int wgid = ((int)blockIdx.x & 7) * cpx + ((int)blockIdx.x >> 3);
  const int mblk = (wgid / nxn) * 256;
  const int nblk = (wgid % nxn) * 256;
  const int NT = K >> 6, NI = NT >> 1;

  // staging: thread t covers row (t>>3) [+64 for 2nd issue], slot t&7, src granule pre-swizzled
  const int sg8 = 8 * ((tid & 7) ^ ((tid >> 3) & 7));
  const ushort* As0 = A + (size_t)(mblk + (tid >> 3)) * K + sg8;
  const ushort* Bs0 = Bt + (size_t)(nblk + (tid >> 3)) * K + sg8;
  const size_t r64 = (size_t)64 * K;
  const int wl512 = w * 512;

  auto stage = [&](int isB, int kt, int half, int bufb) {
    const ushort* s = (isB ? Bs0 : As0) + (size_t)kt * 64 + (size_t)(half * 128) * K;
    const int d = bufb + isB * 16384 + half * 8192 + wl512;
    GLDS(s, &lds[d]);
    GLDS(s + r64, &lds[d + 4096]);
  };

  // ds-read bases (ushort idx)
  const int axk0 = ((lg) ^ (lrow & 7)) << 3;
  const int axk1 = ((4 + lg) ^ (lrow & 7)) << 3;
  const int arow = (wm2a + lrow) * 64;
  const int brow = 16384 + (wn2a + lrow) * 64;

  s16x8 af[4][2], bf0[2][2], bf1[2][2];
  const f32x4 zero = {0.f, 0.f, 0.f, 0.f};
  f32x4 acc[2][2][4][2];
#pragma unroll
  for (int qm = 0; qm < 2; qm++)
#pragma unroll
    for (int qn = 0; qn < 2; qn++)
#pragma unroll
      for (int mf = 0; mf < 4; mf++)
#pragma unroll
        for (int nf = 0; nf < 2; nf++) acc[qm][qn][mf][nf] = zero;

#define LOADA(qm, bb) { \
  _Pragma("unroll") for (int mf = 0; mf < 4; mf++) { \
    af[mf][0] = *(const s16x8*)&lds[(bb) + (qm) * 8192 + arow + mf * 1024 + axk0]; \
    af[mf][1] = *(const s16x8*)&lds[(bb) + (qm) * 8192 + arow + mf * 1024 + axk1]; } }
#define LOADB(qn, bb, bfr) { \
  _Pragma("unroll") for (int nf = 0; nf < 2; nf++) { \
    bfr[nf][0] = *(const s16x8*)&lds[(bb) + (qn) * 8192 + brow + nf * 1024 + axk0]; \
    bfr[nf][1] = *(const s16x8*)&lds[(bb) + (qn) * 8192 + brow + nf * 1024 + axk1]; } }
#define MMA(qm, qn, bfr) { \
  __builtin_amdgcn_s_setprio(1); \
  _Pragma("unroll") for (int mf = 0; mf < 4; mf++) \
    _Pragma("unroll") for (int nf = 0; nf < 2; nf++) { \
      acc[qm][qn][mf][nf] = __builtin_amdgcn_mfma_f32_16x16x32_bf16(af[mf][0], bfr[nf][0], acc[qm][qn][mf][nf], 0, 0, 0); \
      acc[qm][qn][mf][nf] = __builtin_amdgcn_mfma_f32_16x16x32_bf16(af[mf][1], bfr[nf][1], acc[qm][qn][mf][nf], 0, 0, 0); } \
  __builtin_amdgcn_s_setprio(0); }
#define BAR() __builtin_amdgcn_s_barrier()

  // prologue: tile 0 -> buf0, tile 1 -> buf1
  stage(0, 0, 0, 0);  stage(0, 0, 1, 0);  stage(1, 0, 0, 0);  stage(1, 0, 1, 0);
  stage(0, 1, 0, SB); stage(0, 1, 1, SB); stage(1, 1, 0, SB); stage(1, 1, 1, SB);
  waitvm<8>(); BAR();

  for (int it = 0; it < NI; ++it) {
    const bool sB1 = (it > 0);
    const bool sA2 = (2 * it + 2 < NT);
    const bool sB2 = (2 * it + 3 < NT);
    const int kb1 = 2 * it + 1, ka2 = 2 * it + 2, kb2 = 2 * it + 3;

    // ---- buf0 tile (2*it) ----
    // ph1: Q(0,0)
    LOADA(0, 0); LOADB(0, 0, bf0);
    if (sB1) stage(0, kb1, 1, SB);        // Ah1(b1) -> buf1
    BAR(); MMA(0, 0, bf0); BAR();
    // ph2: Q(0,1)
    LOADB(1, 0, bf1);
    if (sB1) stage(1, kb1, 0, SB);        // Bh0(b1) -> buf1
    BAR(); MMA(0, 1, bf1); BAR();
    // ph3: Q(1,1)
    LOADA(1, 0);
    if (sA2) stage(0, ka2, 0, 0);         // Ah0(a2) -> buf0
    BAR(); MMA(1, 1, bf1);
    BAR();
    // ph4: Q(1,0)  (no ds reads; bf0 held)
    if (sA2) stage(1, ka2, 1, 0);         // Bh1(a2) -> buf0
    BAR(); MMA(1, 0, bf0);
    if (it == NI - 1) waitvm<0>(); else waitvm<4>();
    BAR();

    // ---- buf1 tile (2*it+1) ----
    // ph5: Q(0,0)
    LOADA(0, SB); LOADB(0, SB, bf0);
    if (sA2) stage(0, ka2, 1, 0);         // Ah1(a2) -> buf0
    BAR(); MMA(0, 0, bf0); BAR();
    // ph6: Q(0,1)
    LOADB(1, SB, bf1);
    if (sA2) stage(1, ka2, 0, 0);         // Bh0(a2) -> buf0
    BAR(); MMA(0, 1, bf1); BAR();
    // ph7: Q(1,1)
    LOADA(1, SB);
    if (sB2) stage(0, kb2, 0, SB);        // Ah0(b2) -> buf1
    BAR(); MMA(1, 1, bf1); BAR();
    // ph8: Q(1,0)
    if (sB2) stage(1, kb2, 1, SB);        // Bh1(b2) -> buf1
    BAR(); MMA(1, 0, bf0);
    if (it + 1 < NI) {
      if (it + 1 == NI - 1) waitvm<0>(); else waitvm<4>();
      BAR();
    }
  }
#undef LOADA
#undef LOADB
#undef MMA
#undef BAR

  // bias per (qn, nf) column
  float bias_n[2][2];
#pragma unroll
  for (int qn = 0; qn < 2; qn++)
#pragma unroll
    for (int nf = 0; nf < 2; nf++) {
      const int col = nblk + qn * 128 + wn2a + nf * 16 + lrow;
      if (bias1) bias_n[qn][nf] = (col < 1024) ? bias0[col]
                                 : (col < 2048 ? bias1[col - 1024] : bias2[col - 2048]);
      else bias_n[qn][nf] = bias0[col];
    }

  __syncthreads();   // all LDS traffic done; reuse LDS as C staging

  if constexpr (OUTBF16) {
    ushort* Ct = lds;  // [256][256] bf16 = 128KB, exact fit
#pragma unroll
    for (int qm = 0; qm < 2; qm++)
#pragma unroll
      for (int qn = 0; qn < 2; qn++)
#pragma unroll
        for (int mf = 0; mf < 4; mf++)
#pragma unroll
          for (int nf = 0; nf < 2; nf++) {
            f32x4 v = acc[qm][qn][mf][nf];
#pragma unroll
            for (int i = 0; i < 4; i++)
              Ct[(qm * 128 + wm2a + mf * 16 + 4 * lg + i) * 256 +
                 qn * 128 + wn2a + nf * 16 + lrow] = f2bf(v[i] + bias_n[qn][nf]);
          }
    __syncthreads();
    ushort* Cg = (ushort*)Cout;
#pragma unroll
    for (int p = 0; p < 16; p++) {
      const unsigned g = p * 512 + tid;
      const unsigned row = g >> 5, c8 = g & 31;
      *(s16x8*)&Cg[(size_t)(mblk + row) * N + nblk + c8 * 8] = *(const s16x8*)&lds[g * 8];
    }
  } else {
    float* Cf = (float*)lds;  // [64][256] f32 = 64KB chunk
    float* Cg = (float*)Cout;
#pragma unroll
    for (int c = 0; c < 4; c++) {
      __syncthreads();
      if ((w >> 2) == (c & 1)) {
        const int qm = c >> 1;
#pragma unroll
        for (int qn = 0; qn < 2; qn++)
#pragma unroll
          for (int mf = 0; mf < 4; mf++)
#pragma unroll
            for (int nf = 0; nf < 2; nf++) {
              f32x4 v = acc[qm][qn][mf][nf];
#pragma unroll
              for (int i = 0; i < 4; i++)
                Cf[(mf * 16 + 4 * lg + i) * 256 + qn * 128 + wn2a + nf * 16 + lrow] =
                    v[i] + bias_n[qn][nf];
            }
      }
      __syncthreads();
#pragma unroll
      for (int p = 0; p < 8; p++) {
        const unsigned fg = p * 512 + tid;
        const unsigned row = fg >> 6, c4 = fg & 63;
        *(float4*)&Cg[(size_t)(mblk + c * 64 + row) * N + nblk + c4 * 4] =
            *(const float4*)&Cf[fg * 4];
      }
    }
  }
}

// ---------------- banded / global flash attention (balanced) ----------------
__global__ __launch_bounds__(256) void attn_kernel(const ushort* __restrict__ qkv,
                                                   ushort* __restrict__ outp,
                                                   float* __restrict__ oPart,
                                                   float* __restrict__ mPart,
                                                   float* __restrict__ lPart)
{
  __shared__ __align__(16) ushort Ks[64 * 64];
  __shared__ __align__(16) ushort Vt[64 * 64];
  __shared__ __align__(16) ushort Ps[4][16 * 40];

  const int tid = threadIdx.x;
  const int w = tid >> 6, lane = tid & 63;
  const int lrow = lane & 15, lg = lane >> 4;

  const int bid = (blockIdx.x & 7) * 368 + (blockIdx.x >> 3);
  int h, b, bx, kv_lo, kv_hi, chunk = 0;
  bool isGlobal;
  if (bid < 1024) {
    isGlobal = true; h = 0;
    chunk = bid >> 7;
    int qb = bid & 127;
    b = qb >> 5; bx = qb & 31;
    kv_lo = chunk * 256; kv_hi = kv_lo + 256;
  } else {
    isGlobal = false;
    int t = bid - 1024;
    h = 1 + (t >> 7);
    int qb = t & 127;
    b = qb >> 5; bx = qb & 31;
    kv_lo = bx * 64 - 128; if (kv_lo < 0) kv_lo = 0;
    kv_hi = bx * 64 + 192; if (kv_hi > 2048) kv_hi = 2048;
  }
  const int q0b = bx * 64;
  const int q0 = q0b + w * 16;
  const ushort* Qp = qkv + (size_t)b * 2048 * 3072 + h * 64;
  const ushort* Kp = Qp + 1024;
  const ushort* Vp = Qp + 2048;

  s16x8 qf0 = *(const s16x8*)(Qp + (size_t)(q0 + lrow) * 3072 + 8 * lg);
  s16x8 qf1 = *(const s16x8*)(Qp + (size_t)(q0 + lrow) * 3072 + 32 + 8 * lg);

  const f32x4 zero = {0.f, 0.f, 0.f, 0.f};
  f32x4 o[4];
  o[0] = zero; o[1] = zero; o[2] = zero; o[3] = zero;
  float mrun = -3e38f, lsum = 0.f;
  const int q_abs = q0 + lrow;
  const float SCL = 0.18033688011112042f;  // 1/8 * log2(e)

  const int sp = tid >> 3;
  const int sg = tid & 7;
  const int kr0 = tid >> 3;
  const int kc = tid & 7;
  const int vx = (lrow & 7) ^ (lrow >> 3);

  for (int kv = kv_lo; kv < kv_hi; kv += 64) {
    const bool needMask = !isGlobal && (kv < q0b - 64 || kv + 64 > q0b + 128);

    const ushort* vrow = Vp + (size_t)(kv + 2 * sp) * 3072 + 8 * sg;
    s16x8 vlo = *(const s16x8*)vrow;
    s16x8 vhi = *(const s16x8*)(vrow + 3072);

    __syncthreads();

    GLDS(Kp + (size_t)(kv + kr0) * 3072 + 8 * (kc ^ (kr0 & 7)), &Ks[w * 512]);
    GLDS(Kp + (size_t)(kv + 32 + kr0) * 3072 + 8 * (kc ^ (kr0 & 7)), &Ks[2048 + w * 512]);

#pragma unroll
    for (int j = 0; j < 8; j++) {
      const int d = 8 * sg + j;
      const int r = 2 * sp;
      uint pk = (uint)(ushort)vlo[j] | ((uint)(ushort)vhi[j] << 16);
      *(uint*)&Vt[d * 64 + ((((r >> 3) ^ j ^ sg) & 7) << 3) + (r & 7)] = pk;
    }
    __syncthreads();

#pragma unroll
    for (int s = 0; s < 2; s++) {
      const int kb = kv + 32 * s;
      const int rs = 32 * s;
      s16x8 kA0 = *(const s16x8*)&Ks[(rs + lrow) * 64      + ((( lg      ^ (lrow & 7)) & 7) << 3)];
      s16x8 kA1 = *(const s16x8*)&Ks[(rs + lrow) * 64      + ((((4 + lg) ^ (lrow & 7)) & 7) << 3)];
      s16x8 kB0 = *(const s16x8*)&Ks[(rs + 16 + lrow) * 64 + ((( lg      ^ (lrow & 7)) & 7) << 3)];
      s16x8 kB1 = *(const s16x8*)&Ks[(rs + 16 + lrow) * 64 + ((((4 + lg) ^ (lrow & 7)) & 7) << 3)];

      f32x4 sA = __builtin_amdgcn_mfma_f32_16x16x32_bf16(kA0, qf0, zero, 0, 0, 0);
      sA = __builtin_amdgcn_mfma_f32_16x16x32_bf16(kA1, qf1, sA, 0, 0, 0);
      f32x4 sB = __builtin_amdgcn_mfma_f32_16x16x32_bf16(kB0, qf0, zero, 0, 0, 0);
      sB = __builtin_amdgcn_mfma_f32_16x16x32_bf16(kB1, qf1, sB, 0, 0, 0);

      float pA[4], pB[4];
      float rowmax = -3e38f;
      if (needMask) {
#pragma unroll
        for (int i = 0; i < 4; i++) {
          int kaA = kb + 4 * lg + i;
          int dq = q_abs - kaA;
          float va = (dq <= 128 && dq >= -128) ? sA[i] * SCL : -1e30f;
          pA[i] = va; rowmax = fmaxf(rowmax, va);
          int dqb = dq - 16;
          float vb = (dqb <= 128 && dqb >= -128) ? sB[i] * SCL : -1e30f;
          pB[i] = vb; rowmax = fmaxf(rowmax, vb);
        }
      } else {
#pragma unroll
        for (int i = 0; i < 4; i++) {
          pA[i] = sA[i] * SCL; pB[i] = sB[i] * SCL;
          rowmax = fmaxf(rowmax, fmaxf(pA[i], pB[i]));
        }
      }
      rowmax = fmaxf(rowmax, __shfl_xor(rowmax, 16));
      rowmax = fmaxf(rowmax, __shfl_xor(rowmax, 32));

      if (!__all(rowmax <= mrun + 8.f)) {
        float mnew = fmaxf(mrun, rowmax);
        float alpha = exp2f(mrun - mnew);
        mrun = mnew;
        lsum *= alpha;
        float a0 = __shfl(alpha, 4 * lg + 0);
        float a1 = __shfl(alpha, 4 * lg + 1);
        float a2 = __shfl(alpha, 4 * lg + 2);
        float a3 = __shfl(alpha, 4 * lg + 3);
#pragma unroll
        for (int c = 0; c < 4; c++) {
          o[c][0] *= a0; o[c][1] *= a1; o[c][2] *= a2; o[c][3] *= a3;
        }
      }

      float rsum = 0.f;
      if (needMask) {
#pragma unroll
        for (int i = 0; i < 4; i++) {
          pA[i] = (pA[i] > -1e29f) ? exp2f(pA[i] - mrun) : 0.f;
          pB[i] = (pB[i] > -1e29f) ? exp2f(pB[i] - mrun) : 0.f;
          rsum += pA[i] + pB[i];
        }
      } else {
#pragma unroll
        for (int i = 0; i < 4; i++) {
          pA[i] = exp2f(pA[i] - mrun);
          pB[i] = exp2f(pB[i] - mrun);
          rsum += pA[i] + pB[i];
        }
      }
      rsum += __shfl_xor(rsum, 16);
      rsum += __shfl_xor(rsum, 32);
      lsum += rsum;

      {
        ushort* P = &Ps[w][lrow * 40];
        *(uint*)&P[4 * lg]      = (uint)f2bf(pA[0]) | ((uint)f2bf(pA[1]) << 16);
        *(uint*)&P[4 * lg + 2]  = (uint)f2bf(pA[2]) | ((uint)f2bf(pA[3]) << 16);
        *(uint*)&P[16 + 4 * lg] = (uint)f2bf(pB[0]) | ((uint)f2bf(pB[1]) << 16);
        *(uint*)&P[18 + 4 * lg] = (uint)f2bf(pB[2]) | ((uint)f2bf(pB[3]) << 16);
      }
      s16x8 paf = *(const s16x8*)&Ps[w][lrow * 40 + 8 * lg];

#pragma unroll
      for (int c = 0; c < 4; c++) {
        const int d = 16 * c + lrow;
        s16x8 vf = *(const s16x8*)&Vt[d * 64 + ((((4 * s + lg) ^ vx ^ (2 * c)) & 7) << 3)];
        o[c] = __builtin_amdgcn_mfma_f32_16x16x32_bf16(paf, vf, o[c], 0, 0, 0);
      }
    }
  }

  if (isGlobal) {
    const size_t rbase = (size_t)(chunk * 4 + b) * 2048 + q0;
    if (lg == 0) {
      mPart[rbase + lrow] = mrun;
      lPart[rbase + lrow] = lsum;
    }
#pragma unroll
    for (int c = 0; c < 4; c++)
#pragma unroll
      for (int i = 0; i < 4; i++)
        oPart[(rbase + 4 * lg + i) * 64 + 16 * c + lrow] = o[c][i];
  } else {
    float li0 = 1.f / __shfl(lsum, 4 * lg + 0);
    float li1 = 1.f / __shfl(lsum, 4 * lg + 1);
    float li2 = 1.f / __shfl(lsum, 4 * lg + 2);
    float li3 = 1.f / __shfl(lsum, 4 * lg + 3);
    size_t orow = (size_t)(b * 2048 + q0 + 4 * lg);
#pragma unroll
    for (int c = 0; c < 4; c++) {
      outp[(orow + 0) * 1024 + h * 64 + 16 * c + lrow] = f2bf(o[c][0] * li0);
      outp[(orow + 1) * 1024 + h * 64 + 16 * c + lrow] = f2bf(o[c][1] * li1);
      outp[(orow + 2) * 1024 + h * 64 + 16 * c + lrow] = f2bf(o[c][2] * li2);
      outp[(orow + 3) * 1024 + h * 64 + 16 * c + lrow] = f2bf(o[c][3] * li3);
    }
  }
}

// ---------------- combine global-head partials ----------------
__global__ __launch_bounds__(256) void combine_kernel(const float* __restrict__ oPart,
                                                      const float* __restrict__ mPart,
                                                      const float* __restrict__ lPart,
                                                      ushort* __restrict__ attno) {
  const int tid = threadIdx.x;
  const int row = blockIdx.x * 64 + (tid >> 2);
  const int d0 = (tid & 3) * 16;
  float m[8], l[8], M = -3e38f;
#pragma unroll
  for (int p = 0; p < 8; p++) {
    m[p] = mPart[p * 8192 + row];
    l[p] = lPart[p * 8192 + row];
    M = fmaxf(M, m[p]);
  }
  float L = 0.f, wgt[8];
#pragma unroll
  for (int p = 0; p < 8; p++) { wgt[p] = exp2f(m[p] - M); L += wgt[p] * l[p]; }
  float inv = 1.f / L;
  float acc[16];
#pragma unroll
  for (int j = 0; j < 16; j++) acc[j] = 0.f;
#pragma unroll
  for (int p = 0; p < 8; p++) {
    const float* op = oPart + ((size_t)p * 8192 + row) * 64 + d0;
    float wv = wgt[p];
#pragma unroll
    for (int j = 0; j < 16; j += 4) {
      float4 v = *(const float4*)(op + j);
      acc[j]     += wv * v.x; acc[j + 1] += wv * v.y;
      acc[j + 2] += wv * v.z; acc[j + 3] += wv * v.w;
    }
  }
  ushort* dst = attno + (size_t)row * 1024 + d0;
#pragma unroll
  for (int j = 0; j < 16; j++) dst[j] = f2bf(acc[j] * inv);
}

// ---------------- launch ----------------
extern "C" void kernel_launch(void* const* d_in, const int* in_sizes, int n_in,
                              void* d_out, int out_size, void* d_ws, size_t ws_size,
                              hipStream_t stream) {
  const float* x  = (const float*)d_in[0];
  const float* wq = (const float*)d_in[1];
  const float* bq = (const float*)d_in[2];
  const float* wk = (const float*)d_in[3];
  const float* bk = (const float*)d_in[4];
  const float* wv = (const float*)d_in[5];
  const float* bv = (const float*)d_in[6];
  const float* wo = (const float*)d_in[7];
  const float* bo = (const float*)d_in[8];

  char* ws = (char*)d_ws;
  ushort* xb    = (ushort*)(ws);                 // 8192x1024 bf16 = 16 MB
  ushort* wqkvb = (ushort*)(ws + 16777216);      // 3072x1024 bf16 =  6 MB
  ushort* wob   = (ushort*)(ws + 23068672);      // 1024x1024 bf16 =  2 MB
  ushort* qkvb  = (ushort*)(ws + 25165824);      // 8192x3072 bf16 = 48 MB
  ushort* attno = (ushort*)(ws + 75497472);      // 8192x1024 bf16 = 16 MB
  float* oPart = (float*)(ws);                   // 8x8192x64 f32 = 16 MB (over xb)
  float* mPart = (float*)(ws + 16777216);
  float* lPart = (float*)(ws + 16777216 + 262144);

  castk<<<8192, 256, 0, stream>>>(x, xb, 8388608);
  castw<<<4096, 256, 0, stream>>>(wq, wk, wv, wo,
                                  wqkvb, wqkvb + 1048576, wqkvb + 2097152, wob);

  // QKV projection: grid 32x12 = 384 blocks (256x256 tiles)
  gemmQ<1><<<384, 512, 0, stream>>>(xb, wqkvb, bq, bk, bv,
                                    (void*)qkvb, 8192, 3072, 1024, 12);

  attn_kernel<<<2944, 256, 0, stream>>>(qkvb, attno, oPart, mPart, lPart);
  combine_kernel<<<128, 256, 0, stream>>>(oPart, mPart, lPart, attno);

  // output projection: grid 32x4 = 128 blocks, f32 out
  gemmQ<0><<<128, 512, 0, stream>>>(attno, wob, bo, nullptr, nullptr,
                                    (void*)d_out, 8192, 1024, 1024, 4);
}

// Round 9
// 172.437 us; speedup vs baseline: 1.0102x; 1.0102x over previous
//
#include <hip/hip_runtime.h>

typedef __attribute__((ext_vector_type(4))) float f32x4;
typedef __attribute__((ext_vector_type(8))) short s16x8;

#define GLDS(gsrc, ldst) \
  __builtin_amdgcn_global_load_lds((const __attribute__((address_space(1))) void*)(gsrc), \
                                   (__attribute__((address_space(3))) void*)(ldst), 16, 0, 0)

__device__ __forceinline__ ushort f2bf(float f) {
  union { float f; unsigned u; } x; x.f = f;
  unsigned r = (x.u + 0x7FFFu + ((x.u >> 16) & 1u)) >> 16;
  return (ushort)r;
}

// ---------------- fused cast f32 -> bf16 (x, wq, wk, wv, wo) ----------------
__global__ __launch_bounds__(256) void castall(
    const float* __restrict__ x, const float* __restrict__ wq, const float* __restrict__ wk,
    const float* __restrict__ wv, const float* __restrict__ wo,
    ushort* __restrict__ xb, ushort* __restrict__ wqkvb, ushort* __restrict__ wob) {
  int bid = blockIdx.x;
  const float* in; ushort* op;
  if (bid < 8192)       { in = x;  op = xb; }
  else if (bid < 9216)  { in = wq; op = wqkvb;           bid -= 8192; }
  else if (bid < 10240) { in = wk; op = wqkvb + 1048576; bid -= 9216; }
  else if (bid < 11264) { in = wv; op = wqkvb + 2097152; bid -= 10240; }
  else                  { in = wo; op = wob;             bid -= 11264; }
  int i = (bid * 256 + threadIdx.x) * 4;
  float4 v = *(const float4*)(in + i);
  ushort4 r;
  r.x = f2bf(v.x); r.y = f2bf(v.y); r.z = f2bf(v.z); r.w = f2bf(v.w);
  *(ushort4*)(op + i) = r;
}

// ---------------- GEMM 128x256, BK=64, 8 waves, triple-buffered (r5 proven) ----------------
template<int OUTBF16>
__global__ __launch_bounds__(512, 2) void gemm256(
    const ushort* __restrict__ A, const ushort* __restrict__ Bt,
    const float* __restrict__ bias0, const float* __restrict__ bias1,
    const float* __restrict__ bias2,
    void* __restrict__ Cout, int M, int N, int K, int nxn)
{
  __shared__ __align__(16) ushort lds[73728];
  const int tid = threadIdx.x;
  const int w = tid >> 6, lane = tid & 63;
  const int lrow = lane & 15, lg = lane >> 4;
  const int wm = w >> 2, wn = w & 3;
  const int cpx = gridDim.x >> 3;
  const int wgid = ((int)blockIdx.x & 7) * cpx + ((int)blockIdx.x >> 3);
  const int mblk = (wgid / nxn) * 128;
  const int nblk = (wgid % nxn) * 256;
  const int NT = K >> 6;

  const int srow = tid >> 3;
  const int scol = 8 * ((tid & 7) ^ (srow & 7));
  const ushort* Abase = A + (size_t)(mblk + srow) * K + scol;
  const ushort* Bbase = Bt + (size_t)(nblk + srow) * K + scol;
  const size_t rstep = (size_t)64 * K;
  const int dA = w * 512;
  const int dB = 8192 + w * 512;

#define STAGE_A(p, bf) { \
    GLDS((p),         &lds[(bf) + dA]); \
    GLDS((p) + rstep, &lds[(bf) + dA + 4096]); }
#define STAGE_B(p, bf) { \
    GLDS((p),             &lds[(bf) + dB]); \
    GLDS((p) + rstep,     &lds[(bf) + dB + 4096]); \
    GLDS((p) + 2 * rstep, &lds[(bf) + dB + 8192]); \
    GLDS((p) + 3 * rstep, &lds[(bf) + dB + 12288]); }

  const int laneA0 = (wm * 64 + lrow) * 64 + ((lg ^ (lrow & 7)) << 3);
  const int laneA1 = (wm * 64 + lrow) * 64 + (((4 + lg) ^ (lrow & 7)) << 3);
  const int laneB0 = 8192 + (wn * 64 + lrow) * 64 + ((lg ^ (lrow & 7)) << 3);
  const int laneB1 = 8192 + (wn * 64 + lrow) * 64 + (((4 + lg) ^ (lrow & 7)) << 3);

  const f32x4 zero = {0.f, 0.f, 0.f, 0.f};
  f32x4 acc[4][4];
#pragma unroll
  for (int m = 0; m < 4; m++)
#pragma unroll
    for (int n = 0; n < 4; n++) acc[m][n] = zero;

  STAGE_A(Abase, 0); STAGE_B(Bbase, 0);
  if (NT > 1) { STAGE_A(Abase + 64, 24576); STAGE_B(Bbase + 64, 24576); }

  const ushort* aP = Abase + 128;
  const ushort* bP = Bbase + 128;
  int bb = 0, bbS = 49152;

  for (int t = 0; t < NT; ++t) {
    if (t < NT - 1) { asm volatile("s_waitcnt vmcnt(6)" ::: "memory"); }
    else            { asm volatile("s_waitcnt vmcnt(0)" ::: "memory"); }
    __builtin_amdgcn_s_barrier();
    const int pA0 = bb + laneA0, pA1 = bb + laneA1;
    const int pB0 = bb + laneB0, pB1 = bb + laneB1;
    const bool pf = (t + 2 < NT);

    if (pf) STAGE_A(aP, bbS);
    {
      s16x8 af[4], bf_[4];
#pragma unroll
      for (int m = 0; m < 4; m++) af[m] = *(const s16x8*)&lds[pA0 + m * 1024];
#pragma unroll
      for (int n = 0; n < 4; n++) bf_[n] = *(const s16x8*)&lds[pB0 + n * 1024];
      __builtin_amdgcn_s_setprio(1);
#pragma unroll
      for (int m = 0; m < 4; m++)
#pragma unroll
        for (int n = 0; n < 4; n++)
          acc[m][n] = __builtin_amdgcn_mfma_f32_16x16x32_bf16(af[m], bf_[n], acc[m][n], 0, 0, 0);
      __builtin_amdgcn_s_setprio(0);
    }
    if (pf) STAGE_B(bP, bbS);
    {
      s16x8 af[4], bf_[4];
#pragma unroll
      for (int m = 0; m < 4; m++) af[m] = *(const s16x8*)&lds[pA1 + m * 1024];
#pragma unroll
      for (int n = 0; n < 4; n++) bf_[n] = *(const s16x8*)&lds[pB1 + n * 1024];
      __builtin_amdgcn_s_setprio(1);
#pragma unroll
      for (int m = 0; m < 4; m++)
#pragma unroll
        for (int n = 0; n < 4; n++)
          acc[m][n] = __builtin_amdgcn_mfma_f32_16x16x32_bf16(af[m], bf_[n], acc[m][n], 0, 0, 0);
      __builtin_amdgcn_s_setprio(0);
    }
    if (pf) { aP += 64; bP += 64; }
    bb  = (bb  == 49152) ? 0 : bb + 24576;
    bbS = (bbS == 49152) ? 0 : bbS + 24576;
  }
#undef STAGE_A
#undef STAGE_B

  float bias_n[4];
#pragma unroll
  for (int n = 0; n < 4; n++) {
    const int col = nblk + wn * 64 + n * 16 + lrow;
    if (bias1) bias_n[n] = (col < 1024) ? bias0[col]
                          : (col < 2048 ? bias1[col - 1024] : bias2[col - 2048]);
    else bias_n[n] = bias0[col];
  }

  __syncthreads();

  if (OUTBF16) {
    ushort* Ct = lds;
#pragma unroll
    for (int m = 0; m < 4; m++)
#pragma unroll
      for (int n = 0; n < 4; n++)
#pragma unroll
        for (int i = 0; i < 4; i++)
          Ct[(wm * 64 + m * 16 + 4 * lg + i) * 256 + wn * 64 + n * 16 + lrow] =
              f2bf(acc[m][n][i] + bias_n[n]);
    __syncthreads();
    ushort* Cg = (ushort*)Cout;
#pragma unroll
    for (int r = 0; r < 8; r++) {
      const int row = r * 16 + (tid >> 5);
      const int col = (tid & 31) * 8;
      *(s16x8*)&Cg[(size_t)(mblk + row) * N + nblk + col] = *(const s16x8*)&lds[r * 4096 + tid * 8];
    }
  } else {
    float* Cf = (float*)lds;
#pragma unroll
    for (int m = 0; m < 4; m++)
#pragma unroll
      for (int n = 0; n < 4; n++)
#pragma unroll
        for (int i = 0; i < 4; i++)
          Cf[(wm * 64 + m * 16 + 4 * lg + i) * 256 + wn * 64 + n * 16 + lrow] =
              acc[m][n][i] + bias_n[n];
    __syncthreads();
    float* Cg = (float*)Cout;
#pragma unroll
    for (int r = 0; r < 16; r++) {
      const int row = r * 8 + (tid >> 6);
      const int col = (tid & 63) * 4;
      *(float4*)&Cg[(size_t)(mblk + row) * N + nblk + col] = *(const float4*)&Cf[r * 2048 + tid * 4];
    }
  }
}

// ---------------- banded / global flash attention (dbuf pipeline) ----------------
__global__ __launch_bounds__(256) void attn_kernel(const ushort* __restrict__ qkv,
                                                   ushort* __restrict__ outp,
                                                   float* __restrict__ oPart,
                                                   float* __restrict__ mPart,
                                                   float* __restrict__ lPart)
{
  __shared__ __align__(16) ushort Ks[2][64 * 64];
  __shared__ __align__(16) ushort Vt[2][64 * 64];
  __shared__ __align__(16) ushort Ps[4][16 * 40];

  const int tid = threadIdx.x;
  const int w = tid >> 6, lane = tid & 63;
  const int lrow = lane & 15, lg = lane >> 4;

  const int bid = (blockIdx.x & 7) * 368 + (blockIdx.x >> 3);
  int h, b, bx, kv_lo, kv_hi, chunk = 0;
  bool isGlobal;
  if (bid < 1024) {
    isGlobal = true; h = 0;
    chunk = bid >> 7;
    int qb = bid & 127;
    b = qb >> 5; bx = qb & 31;
    kv_lo = chunk * 256; kv_hi = kv_lo + 256;
  } else {
    isGlobal = false;
    int t = bid - 1024;
    h = 1 + (t >> 7);
    int qb = t & 127;
    b = qb >> 5; bx = qb & 31;
    kv_lo = bx * 64 - 128; if (kv_lo < 0) kv_lo = 0;
    kv_hi = bx * 64 + 192; if (kv_hi > 2048) kv_hi = 2048;
  }
  const int q0b = bx * 64;
  const int q0 = q0b + w * 16;
  const ushort* Qp = qkv + (size_t)b * 2048 * 3072 + h * 64;
  const ushort* Kp = Qp + 1024;
  const ushort* Vp = Qp + 2048;

  s16x8 qf0 = *(const s16x8*)(Qp + (size_t)(q0 + lrow) * 3072 + 8 * lg);
  s16x8 qf1 = *(const s16x8*)(Qp + (size_t)(q0 + lrow) * 3072 + 32 + 8 * lg);

  const f32x4 zero = {0.f, 0.f, 0.f, 0.f};
  f32x4 o[4];
  o[0] = zero; o[1] = zero; o[2] = zero; o[3] = zero;
  float mrun = -3e38f, lsum = 0.f;
  const int q_abs = q0 + lrow;
  const float SCL = 0.18033688011112042f;  // 1/8 * log2(e)

  const int sp = tid >> 3;
  const int sg = tid & 7;
  const int kr0 = tid >> 3;
  const int kc = tid & 7;
  const int vx = (lrow & 7) ^ (lrow >> 3);

  // prologue: V(t0) -> regs, K(t0) -> Ks[0]
  const ushort* vr0 = Vp + (size_t)(kv_lo + 2 * sp) * 3072 + 8 * sg;
  s16x8 vlo = *(const s16x8*)vr0;
  s16x8 vhi = *(const s16x8*)(vr0 + 3072);
  GLDS(Kp + (size_t)(kv_lo + kr0) * 3072 + 8 * (kc ^ (kr0 & 7)), &Ks[0][w * 512]);
  GLDS(Kp + (size_t)(kv_lo + 32 + kr0) * 3072 + 8 * (kc ^ (kr0 & 7)), &Ks[0][2048 + w * 512]);

  int buf = 0;
  for (int kv = kv_lo; kv < kv_hi; kv += 64) {
    const bool needMask = !isGlobal && (kv < q0b - 64 || kv + 64 > q0b + 128);
    const bool hasNext = (kv + 64 < kv_hi);

    // issue next V loads (latency hides under this tile's compute)
    s16x8 vlon, vhin;
    if (hasNext) {
      const ushort* vr = Vp + (size_t)(kv + 64 + 2 * sp) * 3072 + 8 * sg;
      vlon = *(const s16x8*)vr;
      vhin = *(const s16x8*)(vr + 3072);
    }

    // Vt write for current tile (compiler waits vlo/vhi arrival)
#pragma unroll
    for (int j = 0; j < 8; j++) {
      const int d = 8 * sg + j;
      const int r = 2 * sp;
      uint pk = (uint)(ushort)vlo[j] | ((uint)(ushort)vhi[j] << 16);
      *(uint*)&Vt[buf][d * 64 + ((((r >> 3) ^ j ^ sg) & 7) << 3) + (r & 7)] = pk;
    }
    // wait current-tile K glds (leave next-V in flight), Vt writes done, sync
    if (hasNext) asm volatile("s_waitcnt vmcnt(2)" ::: "memory");
    else         asm volatile("s_waitcnt vmcnt(0)" ::: "memory");
    asm volatile("s_waitcnt lgkmcnt(0)" ::: "memory");
    __builtin_amdgcn_s_barrier();
    // issue next K glds into the other buffer (safe: all waves passed barrier)
    if (hasNext) {
      GLDS(Kp + (size_t)(kv + 64 + kr0) * 3072 + 8 * (kc ^ (kr0 & 7)), &Ks[buf ^ 1][w * 512]);
      GLDS(Kp + (size_t)(kv + 96 + kr0) * 3072 + 8 * (kc ^ (kr0 & 7)), &Ks[buf ^ 1][2048 + w * 512]);
    }

#pragma unroll
    for (int s = 0; s < 2; s++) {
      const int kb = kv + 32 * s;
      const int rs = 32 * s;
      s16x8 kA0 = *(const s16x8*)&Ks[buf][(rs + lrow) * 64      + ((( lg      ^ (lrow & 7)) & 7) << 3)];
      s16x8 kA1 = *(const s16x8*)&Ks[buf][(rs + lrow) * 64      + ((((4 + lg) ^ (lrow & 7)) & 7) << 3)];
      s16x8 kB0 = *(const s16x8*)&Ks[buf][(rs + 16 + lrow) * 64 + ((( lg      ^ (lrow & 7)) & 7) << 3)];
      s16x8 kB1 = *(const s16x8*)&Ks[buf][(rs + 16 + lrow) * 64 + ((((4 + lg) ^ (lrow & 7)) & 7) << 3)];

      f32x4 sA = __builtin_amdgcn_mfma_f32_16x16x32_bf16(kA0, qf0, zero, 0, 0, 0);
      sA = __builtin_amdgcn_mfma_f32_16x16x32_bf16(kA1, qf1, sA, 0, 0, 0);
      f32x4 sB = __builtin_amdgcn_mfma_f32_16x16x32_bf16(kB0, qf0, zero, 0, 0, 0);
      sB = __builtin_amdgcn_mfma_f32_16x16x32_bf16(kB1, qf1, sB, 0, 0, 0);

      float pA[4], pB[4];
      float rowmax = -3e38f;
      if (needMask) {
#pragma unroll
        for (int i = 0; i < 4; i++) {
          int kaA = kb + 4 * lg + i;
          int dq = q_abs - kaA;
          float va = (dq <= 128 && dq >= -128) ? sA[i] * SCL : -1e30f;
          pA[i] = va; rowmax = fmaxf(rowmax, va);
          int dqb = dq - 16;
          float vb = (dqb <= 128 && dqb >= -128) ? sB[i] * SCL : -1e30f;
          pB[i] = vb; rowmax = fmaxf(rowmax, vb);
        }
      } else {
#pragma unroll
        for (int i = 0; i < 4; i++) {
          pA[i] = sA[i] * SCL; pB[i] = sB[i] * SCL;
          rowmax = fmaxf(rowmax, fmaxf(pA[i], pB[i]));
        }
      }
      rowmax = fmaxf(rowmax, __shfl_xor(rowmax, 16));
      rowmax = fmaxf(rowmax, __shfl_xor(rowmax, 32));

      if (!__all(rowmax <= mrun + 8.f)) {
        float mnew = fmaxf(mrun, rowmax);
        float alpha = exp2f(mrun - mnew);
        mrun = mnew;
        lsum *= alpha;
        float a0 = __shfl(alpha, 4 * lg + 0);
        float a1 = __shfl(alpha, 4 * lg + 1);
        float a2 = __shfl(alpha, 4 * lg + 2);
        float a3 = __shfl(alpha, 4 * lg + 3);
#pragma unroll
        for (int c = 0; c < 4; c++) {
          o[c][0] *= a0; o[c][1] *= a1; o[c][2] *= a2; o[c][3] *= a3;
        }
      }

      float rsum = 0.f;
      if (needMask) {
#pragma unroll
        for (int i = 0; i < 4; i++) {
          pA[i] = (pA[i] > -1e29f) ? exp2f(pA[i] - mrun) : 0.f;
          pB[i] = (pB[i] > -1e29f) ? exp2f(pB[i] - mrun) : 0.f;
          rsum += pA[i] + pB[i];
        }
      } else {
#pragma unroll
        for (int i = 0; i < 4; i++) {
          pA[i] = exp2f(pA[i] - mrun);
          pB[i] = exp2f(pB[i] - mrun);
          rsum += pA[i] + pB[i];
        }
      }
      rsum += __shfl_xor(rsum, 16);
      rsum += __shfl_xor(rsum, 32);
      lsum += rsum;

      {
        ushort* P = &Ps[w][lrow * 40];
        *(uint*)&P[4 * lg]      = (uint)f2bf(pA[0]) | ((uint)f2bf(pA[1]) << 16);
        *(uint*)&P[4 * lg + 2]  = (uint)f2bf(pA[2]) | ((uint)f2bf(pA[3]) << 16);
        *(uint*)&P[16 + 4 * lg] = (uint)f2bf(pB[0]) | ((uint)f2bf(pB[1]) << 16);
        *(uint*)&P[18 + 4 * lg] = (uint)f2bf(pB[2]) | ((uint)f2bf(pB[3]) << 16);
      }
      s16x8 paf = *(const s16x8*)&Ps[w][lrow * 40 + 8 * lg];

#pragma unroll
      for (int c = 0; c < 4; c++) {
        const int d = 16 * c + lrow;
        s16x8 vf = *(const s16x8*)&Vt[buf][d * 64 + ((((4 * s + lg) ^ vx ^ (2 * c)) & 7) << 3)];
        o[c] = __builtin_amdgcn_mfma_f32_16x16x32_bf16(paf, vf, o[c], 0, 0, 0);
      }
    }

    vlo = vlon; vhi = vhin;
    buf ^= 1;
  }

  if (isGlobal) {
    const size_t rbase = (size_t)(chunk * 4 + b) * 2048 + q0;
    if (lg == 0) {
      mPart[rbase + lrow] = mrun;
      lPart[rbase + lrow] = lsum;
    }
#pragma unroll
    for (int c = 0; c < 4; c++)
#pragma unroll
      for (int i = 0; i < 4; i++)
        oPart[(rbase + 4 * lg + i) * 64 + 16 * c + lrow] = o[c][i];
  } else {
    float li0 = 1.f / __shfl(lsum, 4 * lg + 0);
    float li1 = 1.f / __shfl(lsum, 4 * lg + 1);
    float li2 = 1.f / __shfl(lsum, 4 * lg + 2);
    float li3 = 1.f / __shfl(lsum, 4 * lg + 3);
    size_t orow = (size_t)(b * 2048 + q0 + 4 * lg);
#pragma unroll
    for (int c = 0; c < 4; c++) {
      outp[(orow + 0) * 1024 + h * 64 + 16 * c + lrow] = f2bf(o[c][0] * li0);
      outp[(orow + 1) * 1024 + h * 64 + 16 * c + lrow] = f2bf(o[c][1] * li1);
      outp[(orow + 2) * 1024 + h * 64 + 16 * c + lrow] = f2bf(o[c][2] * li2);
      outp[(orow + 3) * 1024 + h * 64 + 16 * c + lrow] = f2bf(o[c][3] * li3);
    }
  }
}

// ---------------- combine global-head partials ----------------
__global__ __launch_bounds__(256) void combine_kernel(const float* __restrict__ oPart,
                                                      const float* __restrict__ mPart,
                                                      const float* __restrict__ lPart,
                                                      ushort* __restrict__ attno) {
  const int tid = threadIdx.x;
  const int row = blockIdx.x * 64 + (tid >> 2);
  const int d0 = (tid & 3) * 16;
  float m[8], l[8], M = -3e38f;
#pragma unroll
  for (int p = 0; p < 8; p++) {
    m[p] = mPart[p * 8192 + row];
    l[p] = lPart[p * 8192 + row];
    M = fmaxf(M, m[p]);
  }
  float L = 0.f, wgt[8];
#pragma unroll
  for (int p = 0; p < 8; p++) { wgt[p] = exp2f(m[p] - M); L += wgt[p] * l[p]; }
  float inv = 1.f / L;
  float acc[16];
#pragma unroll
  for (int j = 0; j < 16; j++) acc[j] = 0.f;
#pragma unroll
  for (int p = 0; p < 8; p++) {
    const float* op = oPart + ((size_t)p * 8192 + row) * 64 + d0;
    float wv = wgt[p];
#pragma unroll
    for (int j = 0; j < 16; j += 4) {
      float4 v = *(const float4*)(op + j);
      acc[j]     += wv * v.x; acc[j + 1] += wv * v.y;
      acc[j + 2] += wv * v.z; acc[j + 3] += wv * v.w;
    }
  }
  ushort* dst = attno + (size_t)row * 1024 + d0;
#pragma unroll
  for (int j = 0; j < 16; j++) dst[j] = f2bf(acc[j] * inv);
}

// ---------------- launch ----------------
extern "C" void kernel_launch(void* const* d_in, const int* in_sizes, int n_in,
                              void* d_out, int out_size, void* d_ws, size_t ws_size,
                              hipStream_t stream) {
  const float* x  = (const float*)d_in[0];
  const float* wq = (const float*)d_in[1];
  const float* bq = (const float*)d_in[2];
  const float* wk = (const float*)d_in[3];
  const float* bk = (const float*)d_in[4];
  const float* wv = (const float*)d_in[5];
  const float* bv = (const float*)d_in[6];
  const float* wo = (const float*)d_in[7];
  const float* bo = (const float*)d_in[8];

  char* ws = (char*)d_ws;
  ushort* xb    = (ushort*)(ws);                 // 8192x1024 bf16 = 16 MB
  ushort* wqkvb = (ushort*)(ws + 16777216);      // 3072x1024 bf16 =  6 MB
  ushort* wob   = (ushort*)(ws + 23068672);      // 1024x1024 bf16 =  2 MB
  ushort* qkvb  = (ushort*)(ws + 25165824);      // 8192x3072 bf16 = 48 MB
  ushort* attno = (ushort*)(ws + 75497472);      // 8192x1024 bf16 = 16 MB
  float* oPart = (float*)(ws);                   // 8x8192x64 f32 = 16 MB (over xb)
  float* mPart = (float*)(ws + 16777216);
  float* lPart = (float*)(ws + 16777216 + 262144);

  castall<<<12288, 256, 0, stream>>>(x, wq, wk, wv, wo, xb, wqkvb, wob);

  // QKV projection: [8192,3072]; grid 64x12 = 768 blocks (3 exact rounds at 1 blk/CU)
  gemm256<1><<<768, 512, 0, stream>>>(xb, wqkvb, bq, bk, bv,
                                      (void*)qkvb, 8192, 3072, 1024, 12);

  attn_kernel<<<2944, 256, 0, stream>>>(qkvb, attno, oPart, mPart, lPart);
  combine_kernel<<<128, 256, 0, stream>>>(oPart, mPart, lPart, attno);

  // output projection: grid 64x4 = 256 blocks, f32 out
  gemm256<0><<<256, 512, 0, stream>>>(attno, wob, bo, nullptr, nullptr,
                                      (void*)d_out, 8192, 1024, 1024, 4);
}

// Round 12
// 166.776 us; speedup vs baseline: 1.0445x; 1.0339x over previous
//
#include <hip/hip_runtime.h>

typedef __attribute__((ext_vector_type(4))) float f32x4;
typedef __attribute__((ext_vector_type(16))) float f32x16;
typedef __attribute__((ext_vector_type(8))) short s16x8;

#define GLDS(gsrc, ldst) \
  __builtin_amdgcn_global_load_lds((const __attribute__((address_space(1))) void*)(gsrc), \
                                   (__attribute__((address_space(3))) void*)(ldst), 16, 0, 0)

__device__ __forceinline__ ushort f2bf(float f) {
  union { float f; unsigned u; } x; x.f = f;
  unsigned r = (x.u + 0x7FFFu + ((x.u >> 16) & 1u)) >> 16;
  return (ushort)r;
}

// RNE pack of two f32 -> u32 of 2 bf16 (lo = a, hi = b)
__device__ __forceinline__ uint pkbf(float a, float b) {
  union { float f; uint u; } x, y; x.f = a; y.f = b;
  uint lo = (x.u + 0x7FFFu + ((x.u >> 16) & 1u)) >> 16;
  uint hiw = (y.u + 0x7FFFu + ((y.u >> 16) & 1u)) & 0xFFFF0000u;
  return lo | hiw;
}

__device__ __forceinline__ s16x8 mk_frag(uint x0, uint x1, uint x2, uint x3) {
  union { uint u[4]; s16x8 v; } t;
  t.u[0] = x0; t.u[1] = x1; t.u[2] = x2; t.u[3] = x3;
  return t.v;
}

// ---------------- fused cast f32 -> bf16 (x, wq, wk, wv, wo) ----------------
__global__ __launch_bounds__(256) void castall(
    const float* __restrict__ x, const float* __restrict__ wq, const float* __restrict__ wk,
    const float* __restrict__ wv, const float* __restrict__ wo,
    ushort* __restrict__ xb, ushort* __restrict__ wqkvb, ushort* __restrict__ wob) {
  int bid = blockIdx.x;
  const float* in; ushort* op;
  if (bid < 8192)       { in = x;  op = xb; }
  else if (bid < 9216)  { in = wq; op = wqkvb;           bid -= 8192; }
  else if (bid < 10240) { in = wk; op = wqkvb + 1048576; bid -= 9216; }
  else if (bid < 11264) { in = wv; op = wqkvb + 2097152; bid -= 10240; }
  else                  { in = wo; op = wob;             bid -= 11264; }
  int i = (bid * 256 + threadIdx.x) * 4;
  float4 v = *(const float4*)(in + i);
  ushort4 r;
  r.x = f2bf(v.x); r.y = f2bf(v.y); r.z = f2bf(v.z); r.w = f2bf(v.w);
  *(ushort4*)(op + i) = r;
}

// ---------------- GEMM 128x256, BK=64, 8 waves, triple-buffered (r5 proven) ----------------
template<int OUTBF16>
__global__ __launch_bounds__(512, 2) void gemm256(
    const ushort* __restrict__ A, const ushort* __restrict__ Bt,
    const float* __restrict__ bias0, const float* __restrict__ bias1,
    const float* __restrict__ bias2,
    void* __restrict__ Cout, int M, int N, int K, int nxn)
{
  __shared__ __align__(16) ushort lds[73728];
  const int tid = threadIdx.x;
  const int w = tid >> 6, lane = tid & 63;
  const int lrow = lane & 15, lg = lane >> 4;
  const int wm = w >> 2, wn = w & 3;
  const int cpx = gridDim.x >> 3;
  const int wgid = ((int)blockIdx.x & 7) * cpx + ((int)blockIdx.x >> 3);
  const int mblk = (wgid / nxn) * 128;
  const int nblk = (wgid % nxn) * 256;
  const int NT = K >> 6;

  const int srow = tid >> 3;
  const int scol = 8 * ((tid & 7) ^ (srow & 7));
  const ushort* Abase = A + (size_t)(mblk + srow) * K + scol;
  const ushort* Bbase = Bt + (size_t)(nblk + srow) * K + scol;
  const size_t rstep = (size_t)64 * K;
  const int dA = w * 512;
  const int dB = 8192 + w * 512;

#define STAGE_A(p, bf) { \
    GLDS((p),         &lds[(bf) + dA]); \
    GLDS((p) + rstep, &lds[(bf) + dA + 4096]); }
#define STAGE_B(p, bf) { \
    GLDS((p),             &lds[(bf) + dB]); \
    GLDS((p) + rstep,     &lds[(bf) + dB + 4096]); \
    GLDS((p) + 2 * rstep, &lds[(bf) + dB + 8192]); \
    GLDS((p) + 3 * rstep, &lds[(bf) + dB + 12288]); }

  const int laneA0 = (wm * 64 + lrow) * 64 + ((lg ^ (lrow & 7)) << 3);
  const int laneA1 = (wm * 64 + lrow) * 64 + (((4 + lg) ^ (lrow & 7)) << 3);
  const int laneB0 = 8192 + (wn * 64 + lrow) * 64 + ((lg ^ (lrow & 7)) << 3);
  const int laneB1 = 8192 + (wn * 64 + lrow) * 64 + (((4 + lg) ^ (lrow & 7)) << 3);

  const f32x4 zero = {0.f, 0.f, 0.f, 0.f};
  f32x4 acc[4][4];
#pragma unroll
  for (int m = 0; m < 4; m++)
#pragma unroll
    for (int n = 0; n < 4; n++) acc[m][n] = zero;

  STAGE_A(Abase, 0); STAGE_B(Bbase, 0);
  if (NT > 1) { STAGE_A(Abase + 64, 24576); STAGE_B(Bbase + 64, 24576); }

  const ushort* aP = Abase + 128;
  const ushort* bP = Bbase + 128;
  int bb = 0, bbS = 49152;

  for (int t = 0; t < NT; ++t) {
    if (t < NT - 1) { asm volatile("s_waitcnt vmcnt(6)" ::: "memory"); }
    else            { asm volatile("s_waitcnt vmcnt(0)" ::: "memory"); }
    __builtin_amdgcn_s_barrier();
    const int pA0 = bb + laneA0, pA1 = bb + laneA1;
    const int pB0 = bb + laneB0, pB1 = bb + laneB1;
    const bool pf = (t + 2 < NT);

    if (pf) STAGE_A(aP, bbS);
    {
      s16x8 af[4], bf_[4];
#pragma unroll
      for (int m = 0; m < 4; m++) af[m] = *(const s16x8*)&lds[pA0 + m * 1024];
#pragma unroll
      for (int n = 0; n < 4; n++) bf_[n] = *(const s16x8*)&lds[pB0 + n * 1024];
      __builtin_amdgcn_s_setprio(1);
#pragma unroll
      for (int m = 0; m < 4; m++)
#pragma unroll
        for (int n = 0; n < 4; n++)
          acc[m][n] = __builtin_amdgcn_mfma_f32_16x16x32_bf16(af[m], bf_[n], acc[m][n], 0, 0, 0);
      __builtin_amdgcn_s_setprio(0);
    }
    if (pf) STAGE_B(bP, bbS);
    {
      s16x8 af[4], bf_[4];
#pragma unroll
      for (int m = 0; m < 4; m++) af[m] = *(const s16x8*)&lds[pA1 + m * 1024];
#pragma unroll
      for (int n = 0; n < 4; n++) bf_[n] = *(const s16x8*)&lds[pB1 + n * 1024];
      __builtin_amdgcn_s_setprio(1);
#pragma unroll
      for (int m = 0; m < 4; m++)
#pragma unroll
        for (int n = 0; n < 4; n++)
          acc[m][n] = __builtin_amdgcn_mfma_f32_16x16x32_bf16(af[m], bf_[n], acc[m][n], 0, 0, 0);
      __builtin_amdgcn_s_setprio(0);
    }
    if (pf) { aP += 64; bP += 64; }
    bb  = (bb  == 49152) ? 0 : bb + 24576;
    bbS = (bbS == 49152) ? 0 : bbS + 24576;
  }
#undef STAGE_A
#undef STAGE_B

  float bias_n[4];
#pragma unroll
  for (int n = 0; n < 4; n++) {
    const int col = nblk + wn * 64 + n * 16 + lrow;
    if (bias1) bias_n[n] = (col < 1024) ? bias0[col]
                          : (col < 2048 ? bias1[col - 1024] : bias2[col - 2048]);
    else bias_n[n] = bias0[col];
  }

  __syncthreads();

  if (OUTBF16) {
    ushort* Ct = lds;
#pragma unroll
    for (int m = 0; m < 4; m++)
#pragma unroll
      for (int n = 0; n < 4; n++)
#pragma unroll
        for (int i = 0; i < 4; i++)
          Ct[(wm * 64 + m * 16 + 4 * lg + i) * 256 + wn * 64 + n * 16 + lrow] =
              f2bf(acc[m][n][i] + bias_n[n]);
    __syncthreads();
    ushort* Cg = (ushort*)Cout;
#pragma unroll
    for (int r = 0; r < 8; r++) {
      const int row = r * 16 + (tid >> 5);
      const int col = (tid & 31) * 8;
      *(s16x8*)&Cg[(size_t)(mblk + row) * N + nblk + col] = *(const s16x8*)&lds[r * 4096 + tid * 8];
    }
  } else {
    float* Cf = (float*)lds;
#pragma unroll
    for (int m = 0; m < 4; m++)
#pragma unroll
      for (int n = 0; n < 4; n++)
#pragma unroll
        for (int i = 0; i < 4; i++)
          Cf[(wm * 64 + m * 16 + 4 * lg + i) * 256 + wn * 64 + n * 16 + lrow] =
              acc[m][n][i] + bias_n[n];
    __syncthreads();
    float* Cg = (float*)Cout;
#pragma unroll
    for (int r = 0; r < 16; r++) {
      const int row = r * 8 + (tid >> 6);
      const int col = (tid & 63) * 4;
      *(float4*)&Cg[(size_t)(mblk + row) * N + nblk + col] = *(const float4*)&Cf[r * 2048 + tid * 4];
    }
  }
}

// ---------------- attention: swapped QK^T on 32x32x16, lane-local softmax ----------------
// All cross-half exchanges via __shfl_xor(.,32) (semantics-certain).
__global__ __launch_bounds__(128, 2) void attn_kernel(const ushort* __restrict__ qkv,
                                                      ushort* __restrict__ outp,
                                                      float* __restrict__ oPart,
                                                      float* __restrict__ mPart,
                                                      float* __restrict__ lPart)
{
  __shared__ __align__(16) ushort Ks[2][4096];
  __shared__ __align__(16) ushort Vt[2][4096];

  const int tid = threadIdx.x;
  const int w = tid >> 6, lane = tid & 63;
  const int lq = lane & 31, hi = lane >> 5;

  const int bid = (blockIdx.x & 7) * 368 + (blockIdx.x >> 3);
  int h, b, bx, kv_lo, kv_hi, chunk = 0;
  bool isGlobal;
  if (bid < 1024) {
    isGlobal = true; h = 0;
    chunk = bid >> 7;
    int qb = bid & 127;
    b = qb >> 5; bx = qb & 31;
    kv_lo = chunk * 256; kv_hi = kv_lo + 256;
  } else {
    isGlobal = false;
    int t = bid - 1024;
    h = 1 + (t >> 7);
    int qb = t & 127;
    b = qb >> 5; bx = qb & 31;
    kv_lo = bx * 64 - 128; if (kv_lo < 0) kv_lo = 0;
    kv_hi = bx * 64 + 192; if (kv_hi > 2048) kv_hi = 2048;
  }
  const int q0b = bx * 64;
  const int q0w = q0b + w * 32;
  const int q_abs = q0w + lq;
  const ushort* Qp = qkv + (size_t)b * 2048 * 3072 + h * 64;
  const ushort* Kp = Qp + 1024;
  const ushort* Vp = Qp + 2048;

  s16x8 qf[4];
#pragma unroll
  for (int c = 0; c < 4; c++)
    qf[c] = *(const s16x8*)(Qp + (size_t)q_abs * 3072 + 16 * c + 8 * hi);

  f32x16 o0, o1;
#pragma unroll
  for (int r = 0; r < 16; r++) { o0[r] = 0.f; o1[r] = 0.f; }
  float mrun = -3e38f, lsum = 0.f;
  const float SCL = 0.18033688011112042f;  // 1/8 * log2(e)

  const int kr = tid >> 3, kc = tid & 7;
  const int vsp = tid >> 3, vsg = tid & 7;
  const int kswz = 8 * (kc ^ (kr & 7));

  const ushort* vr0 = Vp + (size_t)(kv_lo + 4 * vsp) * 3072 + 8 * vsg;
  s16x8 v0 = *(const s16x8*)vr0;
  s16x8 v1 = *(const s16x8*)(vr0 + 3072);
  s16x8 v2 = *(const s16x8*)(vr0 + 6144);
  s16x8 v3 = *(const s16x8*)(vr0 + 9216);
#pragma unroll
  for (int i = 0; i < 4; i++)
    GLDS(Kp + (size_t)(kv_lo + 16 * i + kr) * 3072 + kswz, &Ks[0][i * 1024 + w * 512]);

  int buf = 0;
  for (int kv = kv_lo; kv < kv_hi; kv += 64) {
    const bool needMask = !isGlobal && (kv < q0b - 64 || kv + 64 > q0b + 128);
    const bool hasNext = (kv + 64 < kv_hi);

    s16x8 vn0, vn1, vn2, vn3;
    if (hasNext) {
      const ushort* vr = Vp + (size_t)(kv + 64 + 4 * vsp) * 3072 + 8 * vsg;
      vn0 = *(const s16x8*)vr;
      vn1 = *(const s16x8*)(vr + 3072);
      vn2 = *(const s16x8*)(vr + 6144);
      vn3 = *(const s16x8*)(vr + 9216);
    }

#pragma unroll
    for (int j = 0; j < 8; j++) {
      const int d = 8 * vsg + j;
      const int sl = ((vsp >> 1) ^ j ^ vsg) & 7;
      const int a0 = d * 64 + sl * 8 + ((4 * vsp) & 7);
      *(uint*)&Vt[buf][a0]     = (uint)(ushort)v0[j] | ((uint)(ushort)v1[j] << 16);
      *(uint*)&Vt[buf][a0 + 2] = (uint)(ushort)v2[j] | ((uint)(ushort)v3[j] << 16);
    }
    if (hasNext) asm volatile("s_waitcnt vmcnt(4)" ::: "memory");
    else         asm volatile("s_waitcnt vmcnt(0)" ::: "memory");
    asm volatile("s_waitcnt lgkmcnt(0)" ::: "memory");
    __builtin_amdgcn_s_barrier();
    if (hasNext) {
#pragma unroll
      for (int i = 0; i < 4; i++)
        GLDS(Kp + (size_t)(kv + 64 + 16 * i + kr) * 3072 + kswz, &Ks[buf ^ 1][i * 1024 + w * 512]);
    }

    f32x16 s0, s1;
#pragma unroll
    for (int r = 0; r < 16; r++) { s0[r] = 0.f; s1[r] = 0.f; }
#pragma unroll
    for (int c = 0; c < 4; c++) {
      const int gx = ((2 * c + hi) ^ (lq & 7)) << 3;
      s16x8 kf0 = *(const s16x8*)&Ks[buf][lq * 64 + gx];
      s16x8 kf1 = *(const s16x8*)&Ks[buf][(32 + lq) * 64 + gx];
      s0 = __builtin_amdgcn_mfma_f32_32x32x16_bf16(kf0, qf[c], s0, 0, 0, 0);
      s1 = __builtin_amdgcn_mfma_f32_32x32x16_bf16(kf1, qf[c], s1, 0, 0, 0);
    }

    float rm = -3e38f;
    if (needMask) {
#pragma unroll
      for (int r = 0; r < 16; r++) {
        const int kvr = kv + (r & 3) + 8 * (r >> 2) + 4 * hi;
        const int dq0 = q_abs - kvr;
        s0[r] = (dq0 <= 128 && dq0 >= -128) ? s0[r] * SCL : -1e30f;
        const int dq1 = dq0 - 32;
        s1[r] = (dq1 <= 128 && dq1 >= -128) ? s1[r] * SCL : -1e30f;
        rm = fmaxf(rm, fmaxf(s0[r], s1[r]));
      }
    } else {
#pragma unroll
      for (int r = 0; r < 16; r++) {
        s0[r] *= SCL; s1[r] *= SCL;
        rm = fmaxf(rm, fmaxf(s0[r], s1[r]));
      }
    }
    rm = fmaxf(rm, __shfl_xor(rm, 32));

    if (!__all(rm <= mrun + 8.f)) {
      float mnew = fmaxf(mrun, rm);
      float alpha = exp2f(mrun - mnew);
      mrun = mnew;
      lsum *= alpha;
#pragma unroll
      for (int r = 0; r < 16; r++) {
        float av = __shfl(alpha, (r & 3) + 8 * (r >> 2) + 4 * hi);
        o0[r] *= av; o1[r] *= av;
      }
    }

    float rs = 0.f;
#pragma unroll
    for (int r = 0; r < 16; r++) {
      s0[r] = exp2f(s0[r] - mrun); rs += s0[r];
      s1[r] = exp2f(s1[r] - mrun); rs += s1[r];
    }
    rs += __shfl_xor(rs, 32);
    lsum += rs;

    // PV A-frag: lane (lq,hi) needs P[lq][kvbase + 8hi + j], j=0..7.
    // Own regs hold (hi=0): x0={kv0,1} x1={kv2,3} x2={kv8,9} x3={kv10,11};
    //              (hi=1): x0={kv4,5} x1={kv6,7} x2={kv12,13} x3={kv14,15}.
    // Send t0 = hi?x0:x2, t1 = hi?x1:x3; r0/r1 = shfl_xor(t,32); then
    // w0 = hi?r0:x0, w1 = hi?r1:x1, w2 = hi?x2:r0, w3 = hi?x3:r1.
#pragma unroll
    for (int cc = 0; cc < 4; cc++) {
      uint x0, x1, x2, x3;
      if (cc == 0) { x0 = pkbf(s0[0], s0[1]);  x1 = pkbf(s0[2], s0[3]);
                     x2 = pkbf(s0[4], s0[5]);  x3 = pkbf(s0[6], s0[7]); }
      else if (cc == 1) { x0 = pkbf(s0[8], s0[9]);   x1 = pkbf(s0[10], s0[11]);
                          x2 = pkbf(s0[12], s0[13]); x3 = pkbf(s0[14], s0[15]); }
      else if (cc == 2) { x0 = pkbf(s1[0], s1[1]);  x1 = pkbf(s1[2], s1[3]);
                          x2 = pkbf(s1[4], s1[5]);  x3 = pkbf(s1[6], s1[7]); }
      else { x0 = pkbf(s1[8], s1[9]);   x1 = pkbf(s1[10], s1[11]);
             x2 = pkbf(s1[12], s1[13]); x3 = pkbf(s1[14], s1[15]); }
      uint t0 = hi ? x0 : x2;
      uint t1 = hi ? x1 : x3;
      uint r0 = __shfl_xor(t0, 32);
      uint r1 = __shfl_xor(t1, 32);
      uint w0 = hi ? r0 : x0;
      uint w1 = hi ? r1 : x1;
      uint w2 = hi ? x2 : r0;
      uint w3 = hi ? x3 : r1;
      s16x8 pa = mk_frag(w0, w1, w2, w3);
#pragma unroll
      for (int db = 0; db < 2; db++) {
        const int d = 32 * db + lq;
        s16x8 vf = *(const s16x8*)&Vt[buf][d * 64 +
            ((((2 * cc + hi) ^ (d & 7) ^ (d >> 3)) & 7) << 3)];
        if (db == 0) o0 = __builtin_amdgcn_mfma_f32_32x32x16_bf16(pa, vf, o0, 0, 0, 0);
        else         o1 = __builtin_amdgcn_mfma_f32_32x32x16_bf16(pa, vf, o1, 0, 0, 0);
      }
    }

    v0 = vn0; v1 = vn1; v2 = vn2; v3 = vn3;
    buf ^= 1;
  }

  if (isGlobal) {
    const size_t rq = (size_t)(chunk * 4 + b) * 2048 + q0w;
    if (hi == 0) {
      mPart[rq + lq] = mrun;
      lPart[rq + lq] = lsum;
    }
#pragma unroll
    for (int r = 0; r < 16; r++) {
      const int qr = (r & 3) + 8 * (r >> 2) + 4 * hi;
      oPart[(rq + qr) * 64 + lq]      = o0[r];
      oPart[(rq + qr) * 64 + 32 + lq] = o1[r];
    }
  } else {
    float linv = 1.f / lsum;
#pragma unroll
    for (int r = 0; r < 16; r++) {
      const int qr = (r & 3) + 8 * (r >> 2) + 4 * hi;
      float iv = __shfl(linv, qr);
      size_t orow = (size_t)(b * 2048 + q0w + qr) * 1024 + h * 64;
      outp[orow + lq]      = f2bf(o0[r] * iv);
      outp[orow + 32 + lq] = f2bf(o1[r] * iv);
    }
  }
}

// ---------------- combine global-head partials ----------------
__global__ __launch_bounds__(256) void combine_kernel(const float* __restrict__ oPart,
                                                      const float* __restrict__ mPart,
                                                      const float* __restrict__ lPart,
                                                      ushort* __restrict__ attno) {
  const int tid = threadIdx.x;
  const int row = blockIdx.x * 64 + (tid >> 2);
  const int d0 = (tid & 3) * 16;
  float m[8], l[8], M = -3e38f;
#pragma unroll
  for (int p = 0; p < 8; p++) {
    m[p] = mPart[p * 8192 + row];
    l[p] = lPart[p * 8192 + row];
    M = fmaxf(M, m[p]);
  }
  float L = 0.f, wgt[8];
#pragma unroll
  for (int p = 0; p < 8; p++) { wgt[p] = exp2f(m[p] - M); L += wgt[p] * l[p]; }
  float inv = 1.f / L;
  float acc[16];
#pragma unroll
  for (int j = 0; j < 16; j++) acc[j] = 0.f;
#pragma unroll
  for (int p = 0; p < 8; p++) {
    const float* op = oPart + ((size_t)p * 8192 + row) * 64 + d0;
    float wv = wgt[p];
#pragma unroll
    for (int j = 0; j < 16; j += 4) {
      float4 v = *(const float4*)(op + j);
      acc[j]     += wv * v.x; acc[j + 1] += wv * v.y;
      acc[j + 2] += wv * v.z; acc[j + 3] += wv * v.w;
    }
  }
  ushort* dst = attno + (size_t)row * 1024 + d0;
#pragma unroll
  for (int j = 0; j < 16; j++) dst[j] = f2bf(acc[j] * inv);
}

// ---------------- launch ----------------
extern "C" void kernel_launch(void* const* d_in, const int* in_sizes, int n_in,
                              void* d_out, int out_size, void* d_ws, size_t ws_size,
                              hipStream_t stream) {
  const float* x  = (const float*)d_in[0];
  const float* wq = (const float*)d_in[1];
  const float* bq = (const float*)d_in[2];
  const float* wk = (const float*)d_in[3];
  const float* bk = (const float*)d_in[4];
  const float* wv = (const float*)d_in[5];
  const float* bv = (const float*)d_in[6];
  const float* wo = (const float*)d_in[7];
  const float* bo = (const float*)d_in[8];

  char* ws = (char*)d_ws;
  ushort* xb    = (ushort*)(ws);                 // 8192x1024 bf16 = 16 MB
  ushort* wqkvb = (ushort*)(ws + 16777216);      // 3072x1024 bf16 =  6 MB
  ushort* wob   = (ushort*)(ws + 23068672);      // 1024x1024 bf16 =  2 MB
  ushort* qkvb  = (ushort*)(ws + 25165824);      // 8192x3072 bf16 = 48 MB
  ushort* attno = (ushort*)(ws + 75497472);      // 8192x1024 bf16 = 16 MB
  float* oPart = (float*)(ws);                   // 8x8192x64 f32 = 16 MB (over xb)
  float* mPart = (float*)(ws + 16777216);
  float* lPart = (float*)(ws + 16777216 + 262144);

  castall<<<12288, 256, 0, stream>>>(x, wq, wk, wv, wo, xb, wqkvb, wob);

  gemm256<1><<<768, 512, 0, stream>>>(xb, wqkvb, bq, bk, bv,
                                      (void*)qkvb, 8192, 3072, 1024, 12);

  attn_kernel<<<2944, 128, 0, stream>>>(qkvb, attno, oPart, mPart, lPart);
  combine_kernel<<<128, 256, 0, stream>>>(oPart, mPart, lPart, attno);

  gemm256<0><<<256, 512, 0, stream>>>(attno, wob, bo, nullptr, nullptr,
                                      (void*)d_out, 8192, 1024, 1024, 4);
}

// Round 13
// 159.019 us; speedup vs baseline: 1.0954x; 1.0488x over previous
//
#include <hip/hip_runtime.h>

typedef __attribute__((ext_vector_type(4))) float f32x4;
typedef __attribute__((ext_vector_type(16))) float f32x16;
typedef __attribute__((ext_vector_type(8))) short s16x8;

#define GLDS(gsrc, ldst) \
  __builtin_amdgcn_global_load_lds((const __attribute__((address_space(1))) void*)(gsrc), \
                                   (__attribute__((address_space(3))) void*)(ldst), 16, 0, 0)

__device__ __forceinline__ ushort f2bf(float f) {
  union { float f; unsigned u; } x; x.f = f;
  unsigned r = (x.u + 0x7FFFu + ((x.u >> 16) & 1u)) >> 16;
  return (ushort)r;
}

// single-instruction 2^x (avoids ocml denormal-guard expansion)
__device__ __forceinline__ float fexp2(float x) {
  float r;
  asm("v_exp_f32 %0, %1" : "=v"(r) : "v"(x));
  return r;
}

// packed bf16 convert: lo = bf16(a), hi = bf16(b)
__device__ __forceinline__ uint cvtpk(float a, float b) {
  uint r;
  asm("v_cvt_pk_bf16_f32 %0, %1, %2" : "=v"(r) : "v"(a), "v"(b));
  return r;
}

__device__ __forceinline__ s16x8 mk_frag(uint x0, uint x1, uint x2, uint x3) {
  union { uint u[4]; s16x8 v; } t;
  t.u[0] = x0; t.u[1] = x1; t.u[2] = x2; t.u[3] = x3;
  return t.v;
}

// ---------------- fused cast f32 -> bf16 (x, wq, wk, wv, wo) ----------------
__global__ __launch_bounds__(256) void castall(
    const float* __restrict__ x, const float* __restrict__ wq, const float* __restrict__ wk,
    const float* __restrict__ wv, const float* __restrict__ wo,
    ushort* __restrict__ xb, ushort* __restrict__ wqkvb, ushort* __restrict__ wob) {
  int bid = blockIdx.x;
  const float* in; ushort* op;
  if (bid < 8192)       { in = x;  op = xb; }
  else if (bid < 9216)  { in = wq; op = wqkvb;           bid -= 8192; }
  else if (bid < 10240) { in = wk; op = wqkvb + 1048576; bid -= 9216; }
  else if (bid < 11264) { in = wv; op = wqkvb + 2097152; bid -= 10240; }
  else                  { in = wo; op = wob;             bid -= 11264; }
  int i = (bid * 256 + threadIdx.x) * 4;
  float4 v = *(const float4*)(in + i);
  ushort4 r;
  r.x = f2bf(v.x); r.y = f2bf(v.y); r.z = f2bf(v.z); r.w = f2bf(v.w);
  *(ushort4*)(op + i) = r;
}

// ---------------- GEMM 128x256, BK=64, 8 waves, triple-buffered (r5 proven) ----------------
template<int OUTBF16>
__global__ __launch_bounds__(512, 2) void gemm256(
    const ushort* __restrict__ A, const ushort* __restrict__ Bt,
    const float* __restrict__ bias0, const float* __restrict__ bias1,
    const float* __restrict__ bias2,
    void* __restrict__ Cout, int M, int N, int K, int nxn)
{
  __shared__ __align__(16) ushort lds[73728];
  const int tid = threadIdx.x;
  const int w = tid >> 6, lane = tid & 63;
  const int lrow = lane & 15, lg = lane >> 4;
  const int wm = w >> 2, wn = w & 3;
  const int cpx = gridDim.x >> 3;
  const int wgid = ((int)blockIdx.x & 7) * cpx + ((int)blockIdx.x >> 3);
  const int mblk = (wgid / nxn) * 128;
  const int nblk = (wgid % nxn) * 256;
  const int NT = K >> 6;

  const int srow = tid >> 3;
  const int scol = 8 * ((tid & 7) ^ (srow & 7));
  const ushort* Abase = A + (size_t)(mblk + srow) * K + scol;
  const ushort* Bbase = Bt + (size_t)(nblk + srow) * K + scol;
  const size_t rstep = (size_t)64 * K;
  const int dA = w * 512;
  const int dB = 8192 + w * 512;

#define STAGE_A(p, bf) { \
    GLDS((p),         &lds[(bf) + dA]); \
    GLDS((p) + rstep, &lds[(bf) + dA + 4096]); }
#define STAGE_B(p, bf) { \
    GLDS((p),             &lds[(bf) + dB]); \
    GLDS((p) + rstep,     &lds[(bf) + dB + 4096]); \
    GLDS((p) + 2 * rstep, &lds[(bf) + dB + 8192]); \
    GLDS((p) + 3 * rstep, &lds[(bf) + dB + 12288]); }

  const int laneA0 = (wm * 64 + lrow) * 64 + ((lg ^ (lrow & 7)) << 3);
  const int laneA1 = (wm * 64 + lrow) * 64 + (((4 + lg) ^ (lrow & 7)) << 3);
  const int laneB0 = 8192 + (wn * 64 + lrow) * 64 + ((lg ^ (lrow & 7)) << 3);
  const int laneB1 = 8192 + (wn * 64 + lrow) * 64 + (((4 + lg) ^ (lrow & 7)) << 3);

  const f32x4 zero = {0.f, 0.f, 0.f, 0.f};
  f32x4 acc[4][4];
#pragma unroll
  for (int m = 0; m < 4; m++)
#pragma unroll
    for (int n = 0; n < 4; n++) acc[m][n] = zero;

  STAGE_A(Abase, 0); STAGE_B(Bbase, 0);
  if (NT > 1) { STAGE_A(Abase + 64, 24576); STAGE_B(Bbase + 64, 24576); }

  const ushort* aP = Abase + 128;
  const ushort* bP = Bbase + 128;
  int bb = 0, bbS = 49152;

  for (int t = 0; t < NT; ++t) {
    if (t < NT - 1) { asm volatile("s_waitcnt vmcnt(6)" ::: "memory"); }
    else            { asm volatile("s_waitcnt vmcnt(0)" ::: "memory"); }
    __builtin_amdgcn_s_barrier();
    const int pA0 = bb + laneA0, pA1 = bb + laneA1;
    const int pB0 = bb + laneB0, pB1 = bb + laneB1;
    const bool pf = (t + 2 < NT);

    if (pf) STAGE_A(aP, bbS);
    {
      s16x8 af[4], bf_[4];
#pragma unroll
      for (int m = 0; m < 4; m++) af[m] = *(const s16x8*)&lds[pA0 + m * 1024];
#pragma unroll
      for (int n = 0; n < 4; n++) bf_[n] = *(const s16x8*)&lds[pB0 + n * 1024];
      __builtin_amdgcn_s_setprio(1);
#pragma unroll
      for (int m = 0; m < 4; m++)
#pragma unroll
        for (int n = 0; n < 4; n++)
          acc[m][n] = __builtin_amdgcn_mfma_f32_16x16x32_bf16(af[m], bf_[n], acc[m][n], 0, 0, 0);
      __builtin_amdgcn_s_setprio(0);
    }
    if (pf) STAGE_B(bP, bbS);
    {
      s16x8 af[4], bf_[4];
#pragma unroll
      for (int m = 0; m < 4; m++) af[m] = *(const s16x8*)&lds[pA1 + m * 1024];
#pragma unroll
      for (int n = 0; n < 4; n++) bf_[n] = *(const s16x8*)&lds[pB1 + n * 1024];
      __builtin_amdgcn_s_setprio(1);
#pragma unroll
      for (int m = 0; m < 4; m++)
#pragma unroll
        for (int n = 0; n < 4; n++)
          acc[m][n] = __builtin_amdgcn_mfma_f32_16x16x32_bf16(af[m], bf_[n], acc[m][n], 0, 0, 0);
      __builtin_amdgcn_s_setprio(0);
    }
    if (pf) { aP += 64; bP += 64; }
    bb  = (bb  == 49152) ? 0 : bb + 24576;
    bbS = (bbS == 49152) ? 0 : bbS + 24576;
  }
#undef STAGE_A
#undef STAGE_B

  float bias_n[4];
#pragma unroll
  for (int n = 0; n < 4; n++) {
    const int col = nblk + wn * 64 + n * 16 + lrow;
    if (bias1) bias_n[n] = (col < 1024) ? bias0[col]
                          : (col < 2048 ? bias1[col - 1024] : bias2[col - 2048]);
    else bias_n[n] = bias0[col];
  }

  __syncthreads();

  if (OUTBF16) {
    ushort* Ct = lds;
#pragma unroll
    for (int m = 0; m < 4; m++)
#pragma unroll
      for (int n = 0; n < 4; n++)
#pragma unroll
        for (int i = 0; i < 4; i++)
          Ct[(wm * 64 + m * 16 + 4 * lg + i) * 256 + wn * 64 + n * 16 + lrow] =
              f2bf(acc[m][n][i] + bias_n[n]);
    __syncthreads();
    ushort* Cg = (ushort*)Cout;
#pragma unroll
    for (int r = 0; r < 8; r++) {
      const int row = r * 16 + (tid >> 5);
      const int col = (tid & 31) * 8;
      *(s16x8*)&Cg[(size_t)(mblk + row) * N + nblk + col] = *(const s16x8*)&lds[r * 4096 + tid * 8];
    }
  } else {
    float* Cf = (float*)lds;
#pragma unroll
    for (int m = 0; m < 4; m++)
#pragma unroll
      for (int n = 0; n < 4; n++)
#pragma unroll
        for (int i = 0; i < 4; i++)
          Cf[(wm * 64 + m * 16 + 4 * lg + i) * 256 + wn * 64 + n * 16 + lrow] =
              acc[m][n][i] + bias_n[n];
    __syncthreads();
    float* Cg = (float*)Cout;
#pragma unroll
    for (int r = 0; r < 16; r++) {
      const int row = r * 8 + (tid >> 6);
      const int col = (tid & 63) * 4;
      *(float4*)&Cg[(size_t)(mblk + row) * N + nblk + col] = *(const float4*)&Cf[r * 2048 + tid * 4];
    }
  }
}

// ---------------- attention: swapped QK^T on 32x32x16, lane-local softmax ----------------
__global__ __launch_bounds__(128, 2) void attn_kernel(const ushort* __restrict__ qkv,
                                                      ushort* __restrict__ outp,
                                                      float* __restrict__ oPart,
                                                      float* __restrict__ mPart,
                                                      float* __restrict__ lPart)
{
  __shared__ __align__(16) ushort Ks[2][4096];
  __shared__ __align__(16) ushort Vt[2][4096];

  const int tid = threadIdx.x;
  const int w = tid >> 6, lane = tid & 63;
  const int lq = lane & 31, hi = lane >> 5;

  const int bid = (blockIdx.x & 7) * 368 + (blockIdx.x >> 3);
  int h, b, bx, kv_lo, kv_hi, chunk = 0;
  bool isGlobal;
  if (bid < 1024) {
    isGlobal = true; h = 0;
    chunk = bid >> 7;
    int qb = bid & 127;
    b = qb >> 5; bx = qb & 31;
    kv_lo = chunk * 256; kv_hi = kv_lo + 256;
  } else {
    isGlobal = false;
    int t = bid - 1024;
    h = 1 + (t >> 7);
    int qb = t & 127;
    b = qb >> 5; bx = qb & 31;
    kv_lo = bx * 64 - 128; if (kv_lo < 0) kv_lo = 0;
    kv_hi = bx * 64 + 192; if (kv_hi > 2048) kv_hi = 2048;
  }
  const int q0b = bx * 64;
  const int q0w = q0b + w * 32;
  const int q_abs = q0w + lq;
  const ushort* Qp = qkv + (size_t)b * 2048 * 3072 + h * 64;
  const ushort* Kp = Qp + 1024;
  const ushort* Vp = Qp + 2048;

  s16x8 qf[4];
#pragma unroll
  for (int c = 0; c < 4; c++)
    qf[c] = *(const s16x8*)(Qp + (size_t)q_abs * 3072 + 16 * c + 8 * hi);

  f32x16 o0, o1;
#pragma unroll
  for (int r = 0; r < 16; r++) { o0[r] = 0.f; o1[r] = 0.f; }
  float mrun = -3e38f, lsum = 0.f;
  const float SCL = 0.18033688011112042f;  // 1/8 * log2(e)

  const int kr = tid >> 3, kc = tid & 7;
  const int vsp = tid >> 3, vsg = tid & 7;
  const int kswz = 8 * (kc ^ (kr & 7));

  const ushort* vr0 = Vp + (size_t)(kv_lo + 4 * vsp) * 3072 + 8 * vsg;
  s16x8 v0 = *(const s16x8*)vr0;
  s16x8 v1 = *(const s16x8*)(vr0 + 3072);
  s16x8 v2 = *(const s16x8*)(vr0 + 6144);
  s16x8 v3 = *(const s16x8*)(vr0 + 9216);
#pragma unroll
  for (int i = 0; i < 4; i++)
    GLDS(Kp + (size_t)(kv_lo + 16 * i + kr) * 3072 + kswz, &Ks[0][i * 1024 + w * 512]);

  int buf = 0;
  for (int kv = kv_lo; kv < kv_hi; kv += 64) {
    const bool needMask = !isGlobal && (kv < q0b - 64 || kv + 64 > q0b + 128);
    const bool hasNext = (kv + 64 < kv_hi);

    s16x8 vn0, vn1, vn2, vn3;
    if (hasNext) {
      const ushort* vr = Vp + (size_t)(kv + 64 + 4 * vsp) * 3072 + 8 * vsg;
      vn0 = *(const s16x8*)vr;
      vn1 = *(const s16x8*)(vr + 3072);
      vn2 = *(const s16x8*)(vr + 6144);
      vn3 = *(const s16x8*)(vr + 9216);
    }

#pragma unroll
    for (int j = 0; j < 8; j++) {
      const int d = 8 * vsg + j;
      const int sl = ((vsp >> 1) ^ j ^ vsg) & 7;
      const int a0 = d * 64 + sl * 8 + ((4 * vsp) & 7);
      *(uint*)&Vt[buf][a0]     = (uint)(ushort)v0[j] | ((uint)(ushort)v1[j] << 16);
      *(uint*)&Vt[buf][a0 + 2] = (uint)(ushort)v2[j] | ((uint)(ushort)v3[j] << 16);
    }
    if (hasNext) asm volatile("s_waitcnt vmcnt(4)" ::: "memory");
    else         asm volatile("s_waitcnt vmcnt(0)" ::: "memory");
    asm volatile("s_waitcnt lgkmcnt(0)" ::: "memory");
    __builtin_amdgcn_s_barrier();
    if (hasNext) {
#pragma unroll
      for (int i = 0; i < 4; i++)
        GLDS(Kp + (size_t)(kv + 64 + 16 * i + kr) * 3072 + kswz, &Ks[buf ^ 1][i * 1024 + w * 512]);
    }

    f32x16 s0, s1;
#pragma unroll
    for (int r = 0; r < 16; r++) { s0[r] = 0.f; s1[r] = 0.f; }
#pragma unroll
    for (int c = 0; c < 4; c++) {
      const int gx = ((2 * c + hi) ^ (lq & 7)) << 3;
      s16x8 kf0 = *(const s16x8*)&Ks[buf][lq * 64 + gx];
      s16x8 kf1 = *(const s16x8*)&Ks[buf][(32 + lq) * 64 + gx];
      s0 = __builtin_amdgcn_mfma_f32_32x32x16_bf16(kf0, qf[c], s0, 0, 0, 0);
      s1 = __builtin_amdgcn_mfma_f32_32x32x16_bf16(kf1, qf[c], s1, 0, 0, 0);
    }

    // mask (raw-space) + in-lane max; scale once at the end (max is monotone)
    float rm = -3e38f;
    if (needMask) {
#pragma unroll
      for (int r = 0; r < 16; r++) {
        const int kvr = kv + (r & 3) + 8 * (r >> 2) + 4 * hi;
        const int dq0 = q_abs - kvr;
        s0[r] = (dq0 <= 128 && dq0 >= -128) ? s0[r] : -3e38f;
        const int dq1 = dq0 - 32;
        s1[r] = (dq1 <= 128 && dq1 >= -128) ? s1[r] : -3e38f;
        rm = fmaxf(rm, fmaxf(s0[r], s1[r]));
      }
    } else {
#pragma unroll
      for (int r = 0; r < 16; r++) rm = fmaxf(rm, fmaxf(s0[r], s1[r]));
    }
    rm = fmaxf(rm, __shfl_xor(rm, 32)) * SCL;

    if (!__all(rm <= mrun + 8.f)) {
      float mnew = fmaxf(mrun, rm);
      float alpha = fexp2(mrun - mnew);
      mrun = mnew;
      lsum *= alpha;
#pragma unroll
      for (int r = 0; r < 16; r++) {
        float av = __shfl(alpha, (r & 3) + 8 * (r >> 2) + 4 * hi);
        o0[r] *= av; o1[r] *= av;
      }
    }

    // P = 2^(s*SCL - mrun) via fma + 1-instr exp (masked -> -5e37 -> 0)
    float rs = 0.f;
#pragma unroll
    for (int r = 0; r < 16; r++) {
      s0[r] = fexp2(__builtin_fmaf(s0[r], SCL, -mrun)); rs += s0[r];
      s1[r] = fexp2(__builtin_fmaf(s1[r], SCL, -mrun)); rs += s1[r];
    }
    rs += __shfl_xor(rs, 32);
    lsum += rs;

    // PV A-frag: cross-half exchange via shfl_xor(.,32) (r12-proven)
#pragma unroll
    for (int cc = 0; cc < 4; cc++) {
      uint x0, x1, x2, x3;
      if (cc == 0) { x0 = cvtpk(s0[0], s0[1]);  x1 = cvtpk(s0[2], s0[3]);
                     x2 = cvtpk(s0[4], s0[5]);  x3 = cvtpk(s0[6], s0[7]); }
      else if (cc == 1) { x0 = cvtpk(s0[8], s0[9]);   x1 = cvtpk(s0[10], s0[11]);
                          x2 = cvtpk(s0[12], s0[13]); x3 = cvtpk(s0[14], s0[15]); }
      else if (cc == 2) { x0 = cvtpk(s1[0], s1[1]);  x1 = cvtpk(s1[2], s1[3]);
                          x2 = cvtpk(s1[4], s1[5]);  x3 = cvtpk(s1[6], s1[7]); }
      else { x0 = cvtpk(s1[8], s1[9]);   x1 = cvtpk(s1[10], s1[11]);
             x2 = cvtpk(s1[12], s1[13]); x3 = cvtpk(s1[14], s1[15]); }
      uint t0 = hi ? x0 : x2;
      uint t1 = hi ? x1 : x3;
      uint r0 = __shfl_xor(t0, 32);
      uint r1 = __shfl_xor(t1, 32);
      uint w0 = hi ? r0 : x0;
      uint w1 = hi ? r1 : x1;
      uint w2 = hi ? x2 : r0;
      uint w3 = hi ? x3 : r1;
      s16x8 pa = mk_frag(w0, w1, w2, w3);
#pragma unroll
      for (int db = 0; db < 2; db++) {
        const int d = 32 * db + lq;
        s16x8 vf = *(const s16x8*)&Vt[buf][d * 64 +
            ((((2 * cc + hi) ^ (d & 7) ^ (d >> 3)) & 7) << 3)];
        if (db == 0) o0 = __builtin_amdgcn_mfma_f32_32x32x16_bf16(pa, vf, o0, 0, 0, 0);
        else         o1 = __builtin_amdgcn_mfma_f32_32x32x16_bf16(pa, vf, o1, 0, 0, 0);
      }
    }

    v0 = vn0; v1 = vn1; v2 = vn2; v3 = vn3;
    buf ^= 1;
  }

  if (isGlobal) {
    const size_t rq = (size_t)(chunk * 4 + b) * 2048 + q0w;
    if (hi == 0) {
      mPart[rq + lq] = mrun;
      lPart[rq + lq] = lsum;
    }
#pragma unroll
    for (int r = 0; r < 16; r++) {
      const int qr = (r & 3) + 8 * (r >> 2) + 4 * hi;
      oPart[(rq + qr) * 64 + lq]      = o0[r];
      oPart[(rq + qr) * 64 + 32 + lq] = o1[r];
    }
  } else {
    float linv = 1.f / lsum;
#pragma unroll
    for (int r = 0; r < 16; r++) {
      const int qr = (r & 3) + 8 * (r >> 2) + 4 * hi;
      float iv = __shfl(linv, qr);
      size_t orow = (size_t)(b * 2048 + q0w + qr) * 1024 + h * 64;
      outp[orow + lq]      = f2bf(o0[r] * iv);
      outp[orow + 32 + lq] = f2bf(o1[r] * iv);
    }
  }
}

// ---------------- combine global-head partials ----------------
__global__ __launch_bounds__(256) void combine_kernel(const float* __restrict__ oPart,
                                                      const float* __restrict__ mPart,
                                                      const float* __restrict__ lPart,
                                                      ushort* __restrict__ attno) {
  const int tid = threadIdx.x;
  const int row = blockIdx.x * 64 + (tid >> 2);
  const int d0 = (tid & 3) * 16;
  float m[8], l[8], M = -3e38f;
#pragma unroll
  for (int p = 0; p < 8; p++) {
    m[p] = mPart[p * 8192 + row];
    l[p] = lPart[p * 8192 + row];
    M = fmaxf(M, m[p]);
  }
  float L = 0.f, wgt[8];
#pragma unroll
  for (int p = 0; p < 8; p++) { wgt[p] = fexp2(m[p] - M); L += wgt[p] * l[p]; }
  float inv = 1.f / L;
  float acc[16];
#pragma unroll
  for (int j = 0; j < 16; j++) acc[j] = 0.f;
#pragma unroll
  for (int p = 0; p < 8; p++) {
    const float* op = oPart + ((size_t)p * 8192 + row) * 64 + d0;
    float wv = wgt[p];
#pragma unroll
    for (int j = 0; j < 16; j += 4) {
      float4 v = *(const float4*)(op + j);
      acc[j]     += wv * v.x; acc[j + 1] += wv * v.y;
      acc[j + 2] += wv * v.z; acc[j + 3] += wv * v.w;
    }
  }
  ushort* dst = attno + (size_t)row * 1024 + d0;
#pragma unroll
  for (int j = 0; j < 16; j++) dst[j] = f2bf(acc[j] * inv);
}

// ---------------- launch ----------------
extern "C" void kernel_launch(void* const* d_in, const int* in_sizes, int n_in,
                              void* d_out, int out_size, void* d_ws, size_t ws_size,
                              hipStream_t stream) {
  const float* x  = (const float*)d_in[0];
  const float* wq = (const float*)d_in[1];
  const float* bq = (const float*)d_in[2];
  const float* wk = (const float*)d_in[3];
  const float* bk = (const float*)d_in[4];
  const float* wv = (const float*)d_in[5];
  const float* bv = (const float*)d_in[6];
  const float* wo = (const float*)d_in[7];
  const float* bo = (const float*)d_in[8];

  char* ws = (char*)d_ws;
  ushort* xb    = (ushort*)(ws);                 // 8192x1024 bf16 = 16 MB
  ushort* wqkvb = (ushort*)(ws + 16777216);      // 3072x1024 bf16 =  6 MB
  ushort* wob   = (ushort*)(ws + 23068672);      // 1024x1024 bf16 =  2 MB
  ushort* qkvb  = (ushort*)(ws + 25165824);      // 8192x3072 bf16 = 48 MB
  ushort* attno = (ushort*)(ws + 75497472);      // 8192x1024 bf16 = 16 MB
  float* oPart = (float*)(ws);                   // 8x8192x64 f32 = 16 MB (over xb)
  float* mPart = (float*)(ws + 16777216);
  float* lPart = (float*)(ws + 16777216 + 262144);

  castall<<<12288, 256, 0, stream>>>(x, wq, wk, wv, wo, xb, wqkvb, wob);

  gemm256<1><<<768, 512, 0, stream>>>(xb, wqkvb, bq, bk, bv,
                                      (void*)qkvb, 8192, 3072, 1024, 12);

  attn_kernel<<<2944, 128, 0, stream>>>(qkvb, attno, oPart, mPart, lPart);
  combine_kernel<<<128, 256, 0, stream>>>(oPart, mPart, lPart, attno);

  gemm256<0><<<256, 512, 0, stream>>>(attno, wob, bo, nullptr, nullptr,
                                      (void*)d_out, 8192, 1024, 1024, 4);
}

// Round 14
// 153.217 us; speedup vs baseline: 1.1369x; 1.0379x over previous
//
#include <hip/hip_runtime.h>

typedef __attribute__((ext_vector_type(4))) float f32x4;
typedef __attribute__((ext_vector_type(16))) float f32x16;
typedef __attribute__((ext_vector_type(8))) short s16x8;

#define GLDS(gsrc, ldst) \
  __builtin_amdgcn_global_load_lds((const __attribute__((address_space(1))) void*)(gsrc), \
                                   (__attribute__((address_space(3))) void*)(ldst), 16, 0, 0)

__device__ __forceinline__ ushort f2bf(float f) {
  union { float f; unsigned u; } x; x.f = f;
  unsigned r = (x.u + 0x7FFFu + ((x.u >> 16) & 1u)) >> 16;
  return (ushort)r;
}

// single-instruction 2^x (avoids ocml denormal-guard expansion)
__device__ __forceinline__ float fexp2(float x) {
  float r;
  asm("v_exp_f32 %0, %1" : "=v"(r) : "v"(x));
  return r;
}

// packed bf16 convert: lo = bf16(a), hi = bf16(b)
__device__ __forceinline__ uint cvtpk(float a, float b) {
  uint r;
  asm("v_cvt_pk_bf16_f32 %0, %1, %2" : "=v"(r) : "v"(a), "v"(b));
  return r;
}

__device__ __forceinline__ s16x8 mk_frag(uint x0, uint x1, uint x2, uint x3) {
  union { uint u[4]; s16x8 v; } t;
  t.u[0] = x0; t.u[1] = x1; t.u[2] = x2; t.u[3] = x3;
  return t.v;
}

// ---------------- fused cast f32 -> bf16 (x, wq, wk, wv, wo) ----------------
__global__ __launch_bounds__(256) void castall(
    const float* __restrict__ x, const float* __restrict__ wq, const float* __restrict__ wk,
    const float* __restrict__ wv, const float* __restrict__ wo,
    ushort* __restrict__ xb, ushort* __restrict__ wqkvb, ushort* __restrict__ wob) {
  int bid = blockIdx.x;
  const float* in; ushort* op;
  if (bid < 8192)       { in = x;  op = xb; }
  else if (bid < 9216)  { in = wq; op = wqkvb;           bid -= 8192; }
  else if (bid < 10240) { in = wk; op = wqkvb + 1048576; bid -= 9216; }
  else if (bid < 11264) { in = wv; op = wqkvb + 2097152; bid -= 10240; }
  else                  { in = wo; op = wob;             bid -= 11264; }
  int i = (bid * 256 + threadIdx.x) * 4;
  float4 v = *(const float4*)(in + i);
  ushort4 r;
  r.x = f2bf(v.x); r.y = f2bf(v.y); r.z = f2bf(v.z); r.w = f2bf(v.w);
  *(ushort4*)(op + i) = r;
}

// ---------------- GEMM 128x256, BK=64, 8 waves, triple-buffered (r5 proven) ----------------
template<int OUTBF16>
__global__ __launch_bounds__(512, 2) void gemm256(
    const ushort* __restrict__ A, const ushort* __restrict__ Bt,
    const float* __restrict__ bias0, const float* __restrict__ bias1,
    const float* __restrict__ bias2,
    void* __restrict__ Cout, int M, int N, int K, int nxn)
{
  __shared__ __align__(16) ushort lds[73728];
  const int tid = threadIdx.x;
  const int w = tid >> 6, lane = tid & 63;
  const int lrow = lane & 15, lg = lane >> 4;
  const int wm = w >> 2, wn = w & 3;
  const int cpx = gridDim.x >> 3;
  const int wgid = ((int)blockIdx.x & 7) * cpx + ((int)blockIdx.x >> 3);
  const int mblk = (wgid / nxn) * 128;
  const int nblk = (wgid % nxn) * 256;
  const int NT = K >> 6;

  const int srow = tid >> 3;
  const int scol = 8 * ((tid & 7) ^ (srow & 7));
  const ushort* Abase = A + (size_t)(mblk + srow) * K + scol;
  const ushort* Bbase = Bt + (size_t)(nblk + srow) * K + scol;
  const size_t rstep = (size_t)64 * K;
  const int dA = w * 512;
  const int dB = 8192 + w * 512;

#define STAGE_A(p, bf) { \
    GLDS((p),         &lds[(bf) + dA]); \
    GLDS((p) + rstep, &lds[(bf) + dA + 4096]); }
#define STAGE_B(p, bf) { \
    GLDS((p),             &lds[(bf) + dB]); \
    GLDS((p) + rstep,     &lds[(bf) + dB + 4096]); \
    GLDS((p) + 2 * rstep, &lds[(bf) + dB + 8192]); \
    GLDS((p) + 3 * rstep, &lds[(bf) + dB + 12288]); }

  const int laneA0 = (wm * 64 + lrow) * 64 + ((lg ^ (lrow & 7)) << 3);
  const int laneA1 = (wm * 64 + lrow) * 64 + (((4 + lg) ^ (lrow & 7)) << 3);
  const int laneB0 = 8192 + (wn * 64 + lrow) * 64 + ((lg ^ (lrow & 7)) << 3);
  const int laneB1 = 8192 + (wn * 64 + lrow) * 64 + (((4 + lg) ^ (lrow & 7)) << 3);

  const f32x4 zero = {0.f, 0.f, 0.f, 0.f};
  f32x4 acc[4][4];
#pragma unroll
  for (int m = 0; m < 4; m++)
#pragma unroll
    for (int n = 0; n < 4; n++) acc[m][n] = zero;

  STAGE_A(Abase, 0); STAGE_B(Bbase, 0);
  if (NT > 1) { STAGE_A(Abase + 64, 24576); STAGE_B(Bbase + 64, 24576); }

  const ushort* aP = Abase + 128;
  const ushort* bP = Bbase + 128;
  int bb = 0, bbS = 49152;

  for (int t = 0; t < NT; ++t) {
    if (t < NT - 1) { asm volatile("s_waitcnt vmcnt(6)" ::: "memory"); }
    else            { asm volatile("s_waitcnt vmcnt(0)" ::: "memory"); }
    __builtin_amdgcn_s_barrier();
    const int pA0 = bb + laneA0, pA1 = bb + laneA1;
    const int pB0 = bb + laneB0, pB1 = bb + laneB1;
    const bool pf = (t + 2 < NT);

    if (pf) STAGE_A(aP, bbS);
    {
      s16x8 af[4], bf_[4];
#pragma unroll
      for (int m = 0; m < 4; m++) af[m] = *(const s16x8*)&lds[pA0 + m * 1024];
#pragma unroll
      for (int n = 0; n < 4; n++) bf_[n] = *(const s16x8*)&lds[pB0 + n * 1024];
      __builtin_amdgcn_s_setprio(1);
#pragma unroll
      for (int m = 0; m < 4; m++)
#pragma unroll
        for (int n = 0; n < 4; n++)
          acc[m][n] = __builtin_amdgcn_mfma_f32_16x16x32_bf16(af[m], bf_[n], acc[m][n], 0, 0, 0);
      __builtin_amdgcn_s_setprio(0);
    }
    if (pf) STAGE_B(bP, bbS);
    {
      s16x8 af[4], bf_[4];
#pragma unroll
      for (int m = 0; m < 4; m++) af[m] = *(const s16x8*)&lds[pA1 + m * 1024];
#pragma unroll
      for (int n = 0; n < 4; n++) bf_[n] = *(const s16x8*)&lds[pB1 + n * 1024];
      __builtin_amdgcn_s_setprio(1);
#pragma unroll
      for (int m = 0; m < 4; m++)
#pragma unroll
        for (int n = 0; n < 4; n++)
          acc[m][n] = __builtin_amdgcn_mfma_f32_16x16x32_bf16(af[m], bf_[n], acc[m][n], 0, 0, 0);
      __builtin_amdgcn_s_setprio(0);
    }
    if (pf) { aP += 64; bP += 64; }
    bb  = (bb  == 49152) ? 0 : bb + 24576;
    bbS = (bbS == 49152) ? 0 : bbS + 24576;
  }
#undef STAGE_A
#undef STAGE_B

  float bias_n[4];
#pragma unroll
  for (int n = 0; n < 4; n++) {
    const int col = nblk + wn * 64 + n * 16 + lrow;
    if (bias1) bias_n[n] = (col < 1024) ? bias0[col]
                          : (col < 2048 ? bias1[col - 1024] : bias2[col - 2048]);
    else bias_n[n] = bias0[col];
  }

  __syncthreads();

  if (OUTBF16) {
    ushort* Ct = lds;
#pragma unroll
    for (int m = 0; m < 4; m++)
#pragma unroll
      for (int n = 0; n < 4; n++)
#pragma unroll
        for (int i = 0; i < 4; i++)
          Ct[(wm * 64 + m * 16 + 4 * lg + i) * 256 + wn * 64 + n * 16 + lrow] =
              f2bf(acc[m][n][i] + bias_n[n]);
    __syncthreads();
    ushort* Cg = (ushort*)Cout;
#pragma unroll
    for (int r = 0; r < 8; r++) {
      const int row = r * 16 + (tid >> 5);
      const int col = (tid & 31) * 8;
      *(s16x8*)&Cg[(size_t)(mblk + row) * N + nblk + col] = *(const s16x8*)&lds[r * 4096 + tid * 8];
    }
  } else {
    float* Cf = (float*)lds;
#pragma unroll
    for (int m = 0; m < 4; m++)
#pragma unroll
      for (int n = 0; n < 4; n++)
#pragma unroll
        for (int i = 0; i < 4; i++)
          Cf[(wm * 64 + m * 16 + 4 * lg + i) * 256 + wn * 64 + n * 16 + lrow] =
              acc[m][n][i] + bias_n[n];
    __syncthreads();
    float* Cg = (float*)Cout;
#pragma unroll
    for (int r = 0; r < 16; r++) {
      const int row = r * 8 + (tid >> 6);
      const int col = (tid & 63) * 4;
      *(float4*)&Cg[(size_t)(mblk + row) * N + nblk + col] = *(const float4*)&Cf[r * 2048 + tid * 4];
    }
  }
}

// ---------------- attention: 128-q blocks, 4 waves share K/V tiles ----------------
// Block 256 thr = 4 waves; wave w owns q rows q0blk+32w..+31 (lane q = lane&31).
// K/V tiles of 64 staged once per block, consumed by all 4 waves.
// Swapped QK^T on 32x32x16; lane-local softmax; -inf mask sentinel (fully-masked
// wave-tiles are skipped; fully-masked ROWS within active tiles need -inf so the
// rescale/exp path degenerates correctly).
__global__ __launch_bounds__(256, 2) void attn_kernel(const ushort* __restrict__ qkv,
                                                      ushort* __restrict__ outp,
                                                      float* __restrict__ oPart,
                                                      float* __restrict__ mPart,
                                                      float* __restrict__ lPart)
{
  __shared__ __align__(16) ushort Ks[2][4096];
  __shared__ __align__(16) ushort Vt[2][4096];

  const int tid = threadIdx.x;
  const int w = tid >> 6, lane = tid & 63;
  const int lq = lane & 31, hi = lane >> 5;
  const float NINF = -__builtin_inff();

  const int bid = (blockIdx.x & 7) * 184 + (blockIdx.x >> 3);
  int h, b, bx, kv_lo, kv_hi, chunk = 0;
  bool isGlobal;
  if (bid < 512) {
    isGlobal = true; h = 0;
    chunk = bid >> 6;
    int qb = bid & 63;
    b = qb >> 4; bx = qb & 15;
    kv_lo = chunk * 256; kv_hi = kv_lo + 256;
  } else {
    isGlobal = false;
    int t = bid - 512;
    h = 1 + (t >> 6);
    int qb = t & 63;
    b = qb >> 4; bx = qb & 15;
    kv_lo = bx * 128 - 128; if (kv_lo < 0) kv_lo = 0;
    kv_hi = bx * 128 + 256; if (kv_hi > 2048) kv_hi = 2048;
  }
  const int q0blk = bx * 128;
  const int qw = q0blk + 32 * w;
  const int q_abs = qw + lq;
  const ushort* Qp = qkv + (size_t)b * 2048 * 3072 + h * 64;
  const ushort* Kp = Qp + 1024;
  const ushort* Vp = Qp + 2048;

  s16x8 qf[4];
#pragma unroll
  for (int c = 0; c < 4; c++)
    qf[c] = *(const s16x8*)(Qp + (size_t)q_abs * 3072 + 16 * c + 8 * hi);

  f32x16 o0, o1;
#pragma unroll
  for (int r = 0; r < 16; r++) { o0[r] = 0.f; o1[r] = 0.f; }
  float mrun = -3e38f, lsum = 0.f;
  const float SCL = 0.18033688011112042f;  // 1/8 * log2(e)

  // K staging: wave w, issue j covers rows 16w+8j+ (lane>>3), granule lane&7 pre-swizzled
  const int kg = lane >> 3;
  const int kswz = 8 * ((lane & 7) ^ kg);
  const int krow0 = 16 * w + kg;       // + 8j
  // V staging: thread covers rows 2*vsp, 2*vsp+1, granule vsg
  const int vsp = tid >> 3;
  const int vsg = tid & 7;

  // prologue: V(t0)->regs, K(t0)->Ks[0]
  const ushort* vr0 = Vp + (size_t)(kv_lo + 2 * vsp) * 3072 + 8 * vsg;
  s16x8 v0 = *(const s16x8*)vr0;
  s16x8 v1 = *(const s16x8*)(vr0 + 3072);
  GLDS(Kp + (size_t)(kv_lo + krow0) * 3072 + kswz,     &Ks[0][(2 * w) * 512]);
  GLDS(Kp + (size_t)(kv_lo + krow0 + 8) * 3072 + kswz, &Ks[0][(2 * w + 1) * 512]);

  int buf = 0;
  for (int kv = kv_lo; kv < kv_hi; kv += 64) {
    const bool hasNext = (kv + 64 < kv_hi);
    // wave-level: does this tile intersect this wave's band window?
    const bool active = isGlobal || ((kv + 63 >= qw - 128) && (kv <= qw + 159));
    const bool needMask = !isGlobal && active && ((kv < qw - 97) || (kv > qw + 65));

    s16x8 vn0, vn1;
    if (hasNext) {
      const ushort* vr = Vp + (size_t)(kv + 64 + 2 * vsp) * 3072 + 8 * vsg;
      vn0 = *(const s16x8*)vr;
      vn1 = *(const s16x8*)(vr + 3072);
    }

    // Vt transpose-write (current tile): pair (rows 2vsp, 2vsp+1) per d
#pragma unroll
    for (int j = 0; j < 8; j++) {
      const int d = 8 * vsg + j;
      const int sl = ((vsp >> 2) ^ j ^ vsg) & 7;
      *(uint*)&Vt[buf][d * 64 + sl * 8 + ((2 * vsp) & 7)] =
          (uint)(ushort)v0[j] | ((uint)(ushort)v1[j] << 16);
    }
    if (hasNext) asm volatile("s_waitcnt vmcnt(2)" ::: "memory");
    else         asm volatile("s_waitcnt vmcnt(0)" ::: "memory");
    asm volatile("s_waitcnt lgkmcnt(0)" ::: "memory");
    __builtin_amdgcn_s_barrier();
    if (hasNext) {
      GLDS(Kp + (size_t)(kv + 64 + krow0) * 3072 + kswz,     &Ks[buf ^ 1][(2 * w) * 512]);
      GLDS(Kp + (size_t)(kv + 64 + krow0 + 8) * 3072 + kswz, &Ks[buf ^ 1][(2 * w + 1) * 512]);
    }

    if (active) {
      f32x16 s0, s1;
#pragma unroll
      for (int r = 0; r < 16; r++) { s0[r] = 0.f; s1[r] = 0.f; }
#pragma unroll
      for (int c = 0; c < 4; c++) {
        const int gx = ((2 * c + hi) ^ (lq & 7)) << 3;
        s16x8 kf0 = *(const s16x8*)&Ks[buf][lq * 64 + gx];
        s16x8 kf1 = *(const s16x8*)&Ks[buf][(32 + lq) * 64 + gx];
        s0 = __builtin_amdgcn_mfma_f32_32x32x16_bf16(kf0, qf[c], s0, 0, 0, 0);
        s1 = __builtin_amdgcn_mfma_f32_32x32x16_bf16(kf1, qf[c], s1, 0, 0, 0);
      }

      float rm = NINF;
      if (needMask) {
#pragma unroll
        for (int r = 0; r < 16; r++) {
          const int kvr = kv + (r & 3) + 8 * (r >> 2) + 4 * hi;
          const int dq0 = q_abs - kvr;
          s0[r] = (dq0 <= 128 && dq0 >= -128) ? s0[r] : NINF;
          const int dq1 = dq0 - 32;
          s1[r] = (dq1 <= 128 && dq1 >= -128) ? s1[r] : NINF;
          rm = fmaxf(rm, fmaxf(s0[r], s1[r]));
        }
      } else {
#pragma unroll
        for (int r = 0; r < 16; r++) rm = fmaxf(rm, fmaxf(s0[r], s1[r]));
      }
      rm = fmaxf(rm, __shfl_xor(rm, 32)) * SCL;

      if (!__all(rm <= mrun + 8.f)) {
        float mnew = fmaxf(mrun, rm);
        float alpha = fexp2(mrun - mnew);
        mrun = mnew;
        lsum *= alpha;
#pragma unroll
        for (int r = 0; r < 16; r++) {
          float av = __shfl(alpha, (r & 3) + 8 * (r >> 2) + 4 * hi);
          o0[r] *= av; o1[r] *= av;
        }
      }

      float rs = 0.f;
#pragma unroll
      for (int r = 0; r < 16; r++) {
        s0[r] = fexp2(__builtin_fmaf(s0[r], SCL, -mrun)); rs += s0[r];
        s1[r] = fexp2(__builtin_fmaf(s1[r], SCL, -mrun)); rs += s1[r];
      }
      rs += __shfl_xor(rs, 32);
      lsum += rs;

#pragma unroll
      for (int cc = 0; cc < 4; cc++) {
        uint x0, x1, x2, x3;
        if (cc == 0) { x0 = cvtpk(s0[0], s0[1]);  x1 = cvtpk(s0[2], s0[3]);
                       x2 = cvtpk(s0[4], s0[5]);  x3 = cvtpk(s0[6], s0[7]); }
        else if (cc == 1) { x0 = cvtpk(s0[8], s0[9]);   x1 = cvtpk(s0[10], s0[11]);
                            x2 = cvtpk(s0[12], s0[13]); x3 = cvtpk(s0[14], s0[15]); }
        else if (cc == 2) { x0 = cvtpk(s1[0], s1[1]);  x1 = cvtpk(s1[2], s1[3]);
                            x2 = cvtpk(s1[4], s1[5]);  x3 = cvtpk(s1[6], s1[7]); }
        else { x0 = cvtpk(s1[8], s1[9]);   x1 = cvtpk(s1[10], s1[11]);
               x2 = cvtpk(s1[12], s1[13]); x3 = cvtpk(s1[14], s1[15]); }
        uint t0 = hi ? x0 : x2;
        uint t1 = hi ? x1 : x3;
        uint r0 = __shfl_xor(t0, 32);
        uint r1 = __shfl_xor(t1, 32);
        uint w0 = hi ? r0 : x0;
        uint w1 = hi ? r1 : x1;
        uint w2 = hi ? x2 : r0;
        uint w3 = hi ? x3 : r1;
        s16x8 pa = mk_frag(w0, w1, w2, w3);
#pragma unroll
        for (int db = 0; db < 2; db++) {
          const int d = 32 * db + lq;
          s16x8 vf = *(const s16x8*)&Vt[buf][d * 64 +
              ((((2 * cc + hi) ^ (d & 7) ^ (d >> 3)) & 7) << 3)];
          if (db == 0) o0 = __builtin_amdgcn_mfma_f32_32x32x16_bf16(pa, vf, o0, 0, 0, 0);
          else         o1 = __builtin_amdgcn_mfma_f32_32x32x16_bf16(pa, vf, o1, 0, 0, 0);
        }
      }
    }

    v0 = vn0; v1 = vn1;
    buf ^= 1;
  }

  if (isGlobal) {
    const size_t rq = (size_t)(chunk * 4 + b) * 2048 + qw;
    if (hi == 0) {
      mPart[rq + lq] = mrun;
      lPart[rq + lq] = lsum;
    }
#pragma unroll
    for (int r = 0; r < 16; r++) {
      const int qr = (r & 3) + 8 * (r >> 2) + 4 * hi;
      oPart[(rq + qr) * 64 + lq]      = o0[r];
      oPart[(rq + qr) * 64 + 32 + lq] = o1[r];
    }
  } else {
    float linv = 1.f / lsum;
#pragma unroll
    for (int r = 0; r < 16; r++) {
      const int qr = (r & 3) + 8 * (r >> 2) + 4 * hi;
      float iv = __shfl(linv, qr);
      size_t orow = (size_t)(b * 2048 + qw + qr) * 1024 + h * 64;
      outp[orow + lq]      = f2bf(o0[r] * iv);
      outp[orow + 32 + lq] = f2bf(o1[r] * iv);
    }
  }
}

// ---------------- combine global-head partials ----------------
__global__ __launch_bounds__(256) void combine_kernel(const float* __restrict__ oPart,
                                                      const float* __restrict__ mPart,
                                                      const float* __restrict__ lPart,
                                                      ushort* __restrict__ attno) {
  const int tid = threadIdx.x;
  const int row = blockIdx.x * 64 + (tid >> 2);
  const int d0 = (tid & 3) * 16;
  float m[8], l[8], M = -3e38f;
#pragma unroll
  for (int p = 0; p < 8; p++) {
    m[p] = mPart[p * 8192 + row];
    l[p] = lPart[p * 8192 + row];
    M = fmaxf(M, m[p]);
  }
  float L = 0.f, wgt[8];
#pragma unroll
  for (int p = 0; p < 8; p++) { wgt[p] = fexp2(m[p] - M); L += wgt[p] * l[p]; }
  float inv = 1.f / L;
  float acc[16];
#pragma unroll
  for (int j = 0; j < 16; j++) acc[j] = 0.f;
#pragma unroll
  for (int p = 0; p < 8; p++) {
    const float* op = oPart + ((size_t)p * 8192 + row) * 64 + d0;
    float wv = wgt[p];
#pragma unroll
    for (int j = 0; j < 16; j += 4) {
      float4 v = *(const float4*)(op + j);
      acc[j]     += wv * v.x; acc[j + 1] += wv * v.y;
      acc[j + 2] += wv * v.z; acc[j + 3] += wv * v.w;
    }
  }
  ushort* dst = attno + (size_t)row * 1024 + d0;
#pragma unroll
  for (int j = 0; j < 16; j++) dst[j] = f2bf(acc[j] * inv);
}

// ---------------- launch ----------------
extern "C" void kernel_launch(void* const* d_in, const int* in_sizes, int n_in,
                              void* d_out, int out_size, void* d_ws, size_t ws_size,
                              hipStream_t stream) {
  const float* x  = (const float*)d_in[0];
  const float* wq = (const float*)d_in[1];
  const float* bq = (const float*)d_in[2];
  const float* wk = (const float*)d_in[3];
  const float* bk = (const float*)d_in[4];
  const float* wv = (const float*)d_in[5];
  const float* bv = (const float*)d_in[6];
  const float* wo = (const float*)d_in[7];
  const float* bo = (const float*)d_in[8];

  char* ws = (char*)d_ws;
  ushort* xb    = (ushort*)(ws);                 // 8192x1024 bf16 = 16 MB
  ushort* wqkvb = (ushort*)(ws + 16777216);      // 3072x1024 bf16 =  6 MB
  ushort* wob   = (ushort*)(ws + 23068672);      // 1024x1024 bf16 =  2 MB
  ushort* qkvb  = (ushort*)(ws + 25165824);      // 8192x3072 bf16 = 48 MB
  ushort* attno = (ushort*)(ws + 75497472);      // 8192x1024 bf16 = 16 MB
  float* oPart = (float*)(ws);                   // 8x8192x64 f32 = 16 MB (over xb)
  float* mPart = (float*)(ws + 16777216);
  float* lPart = (float*)(ws + 16777216 + 262144);

  castall<<<12288, 256, 0, stream>>>(x, wq, wk, wv, wo, xb, wqkvb, wob);

  gemm256<1><<<768, 512, 0, stream>>>(xb, wqkvb, bq, bk, bv,
                                      (void*)qkvb, 8192, 3072, 1024, 12);

  attn_kernel<<<1472, 256, 0, stream>>>(qkvb, attno, oPart, mPart, lPart);
  combine_kernel<<<128, 256, 0, stream>>>(oPart, mPart, lPart, attno);

  gemm256<0><<<256, 512, 0, stream>>>(attno, wob, bo, nullptr, nullptr,
                                      (void*)d_out, 8192, 1024, 1024, 4);
}